// Round 9
// baseline (14870.218 us; speedup 1.0000x reference)
//
#include <hip/hip_runtime.h>
#include <math.h>

// ---------------------------------------------------------------------------
// observation_processing_network, gfx950.
// R5 6607us CSR gather, 643 grid barriers x 8.7us.
// R6 4832us slice-ownership, 391 barriers x ~11us.
// R7 4692us fence-free barriers -> NO CHANGE: ~10us/global-sync is structural
//   (cross-XCD LLC round trips), independent of fence/launch mechanism.
// R8: SINGLE-BLOCK Lanczos. 1024 threads, one CU. Vectors in LDS; Q in
//   global but private to the block (XCD-L2-resident). Zero grid barriers,
//   zero launch boundaries inside the solve: __syncthreads only (~0.1us).
//   CGS2 numerics identical to the validated chain; teig/ritz/sign/xc in
//   the same block's tail.  GNN stages unchanged from R7.
// ---------------------------------------------------------------------------

#define N    2048
#define NE   131072
#define KL   128
#define TPB  256
#define T1   1024

#define SIGN1 -1.0f
#define SIGN2 -1.0f

// ---------------- device helpers ----------------
__device__ __forceinline__ unsigned fkey(float f){
  unsigned u = __float_as_uint(f);
  return (u & 0x80000000u) ? ~u : (u | 0x80000000u);
}
__device__ __forceinline__ float fkeyinv(unsigned k){
  unsigned u = (k & 0x80000000u) ? (k ^ 0x80000000u) : ~k;
  return __uint_as_float(u);
}
__device__ __forceinline__ unsigned wang(unsigned s){
  s = (s ^ 61u) ^ (s >> 16); s *= 9u; s ^= s >> 4; s *= 0x27d4eb2du; s ^= s >> 15;
  return s;
}
// 256-thread block sum (GNN kernels)
__device__ __forceinline__ float block_sum(float v, float* sh){
  __syncthreads();
  for (int off = 32; off > 0; off >>= 1) v += __shfl_down(v, off);
  int lane = threadIdx.x & 63, w = threadIdx.x >> 6;
  if (lane == 0) sh[w] = v;
  __syncthreads();
  return sh[0] + sh[1] + sh[2] + sh[3];
}
// 1024-thread block sum (16 waves); all threads return the total.
__device__ __forceinline__ float bsum16(float v, float* red){
  for (int o = 32; o > 0; o >>= 1) v += __shfl_down(v, o);
  int wid = threadIdx.x >> 6, lane = threadIdx.x & 63;
  __syncthreads();
  if (lane == 0) red[wid] = v;
  __syncthreads();
  float s = 0.f;
  for (int i = 0; i < 16; i++) s += red[i];   // broadcast reads: conflict-free
  return s;
}

// ---------------- small setup kernels ----------------
__global__ void k_zero(float* p, int n){ int i = blockIdx.x*TPB + threadIdx.x; if (i < n) p[i] = 0.f; }
__global__ void k_deg(const int* ei, float* deg){
  int e = blockIdx.x*TPB + threadIdx.x;
  if (e < NE) atomicAdd(&deg[ei[e]], 1.0f);
}
__global__ void k_nodeinit(const float* deg, float* dinv, float* d2g, float* v1){
  int i = blockIdx.x*TPB + threadIdx.x;
  if (i < N){
    float d = deg[i];
    dinv[i] = d > 0.f ? rsqrtf(d) : 0.f;
    d2g[i]  = rsqrtf(d + 1.f);
    v1[i]   = sqrtf(d / (float)NE);
  }
}
__global__ void k_rowptr(const float* deg, int* rowptr, int* fill){
  __shared__ int part[256];
  __shared__ int off[257];
  int t = threadIdx.x;
  int base = t*8;
  int local[8];
  int s = 0;
  for (int k = 0; k < 8; k++){ local[k] = s; s += (int)deg[base + k]; }
  part[t] = s;
  __syncthreads();
  if (t == 0){ off[0] = 0; for (int i = 0; i < 256; i++) off[i+1] = off[i] + part[i]; }
  __syncthreads();
  int o = off[t];
  for (int k = 0; k < 8; k++){ int v = o + local[k]; rowptr[base+k] = v; fill[base+k] = v; }
  if (t == 255) rowptr[N] = off[256];
}
__global__ void k_csr(const int* ei, int* fill, int* cols){
  int e = blockIdx.x*TPB + threadIdx.x;
  if (e < NE){
    int s = ei[e];
    int pos = atomicAdd(&fill[s], 1);
    cols[pos] = ei[NE + e];
  }
}

// ---------------- single-block Lanczos + teig + ritz + xc ------------------
__global__ __launch_bounds__(1024) void k_lanczos1(
    const int* __restrict__ rowptr, const int* __restrict__ cols,
    const float* __restrict__ dinv, const float* __restrict__ v1,
    const float* __restrict__ x,
    float* __restrict__ Q, float* __restrict__ xc, float* __restrict__ outbuf){
  __shared__ float y_l[N], yn_l[N], z_l[N], dv_l[N], v1_l[N];
  __shared__ int   rp_l[N+1];
  __shared__ float cb[KL+2], cb2[KL+2];
  __shared__ float red[16];
  __shared__ float alpha_l[KL], beta_l[KL], zl[KL];
  __shared__ double ta[KL], tb2[KL];
  __shared__ float ssc[2];        // [0]=scale factor
  __shared__ int   idxs;
  const int tid = threadIdx.x;
  const int wid = tid >> 6, lane = tid & 63;
  const int e0 = tid*2;

  // ---- stage constants + start vector ----
  for (int e = tid; e < N; e += T1){
    dv_l[e] = dinv[e];
    v1_l[e] = v1[e];
    y_l[e]  = (float)(wang(e) & 0xffffffu)*(2.f/16777216.f) - 1.f;
    rp_l[e] = rowptr[e];
  }
  if (tid == 0) rp_l[N] = rowptr[N];
  __syncthreads();
  // ---- deflate v1, normalize -> q0 ----
  {
    float pp = 0.f;
    for (int e = tid; e < N; e += T1) pp += v1_l[e]*y_l[e];
    float c = bsum16(pp, red);
    float nn = 0.f;
    for (int e = tid; e < N; e += T1){
      float v = y_l[e] - c*v1_l[e];
      y_l[e] = v;
      nn += v*v;
    }
    nn = bsum16(nn, red);
    float rn = rsqrtf(nn);
    for (int e = tid; e < N; e += T1){
      float q = y_l[e]*rn;
      y_l[e] = q;
      z_l[e] = dv_l[e]*q;
      Q[e] = q;
    }
  }
  __syncthreads();

  for (int j = 0; j < KL; j++){
    // ---- SpMV: w = L q_j = q_j - dinv .* (A (dinv .* q_j)) ----
    for (int rr = 0; rr < 2; rr++){
      int r = tid + rr*T1;
      int b0 = rp_l[r], b1 = rp_l[r+1];
      float sg = 0.f;
      for (int p = b0; p < b1; p++) sg += z_l[cols[p]];
      yn_l[r] = y_l[r] - dv_l[r]*sg;
    }
    __syncthreads();
    // ---- CGS pass A: dots ----
    for (int i = wid; i <= j+1; i += 16){
      float d = 0.f;
      if (i == j){
        for (int e = lane; e < N; e += 64) d += y_l[e]*yn_l[e];
      } else if (i == j+1){
        for (int e = lane; e < N; e += 64) d += v1_l[e]*yn_l[e];
      } else {
        const float* qi = Q + (size_t)i*N;
        for (int e = lane; e < N; e += 64) d += qi[e]*yn_l[e];
      }
      for (int o = 32; o > 0; o >>= 1) d += __shfl_down(d, o);
      if (lane == 0) cb[i] = d;
    }
    __syncthreads();
    // ---- CGS pass A: subtract ----
    {
      float a0 = 0.f, a1 = 0.f;
      for (int i = 0; i < j; i++){
        float2 q = *(const float2*)(Q + (size_t)i*N + e0);
        a0 += cb[i]*q.x; a1 += cb[i]*q.y;
      }
      a0 += cb[j]*y_l[e0]   + cb[j+1]*v1_l[e0];
      a1 += cb[j]*y_l[e0+1] + cb[j+1]*v1_l[e0+1];
      yn_l[e0]   -= a0;
      yn_l[e0+1] -= a1;
    }
    __syncthreads();
    // ---- CGS pass B: dots ----
    for (int i = wid; i <= j+1; i += 16){
      float d = 0.f;
      if (i == j){
        for (int e = lane; e < N; e += 64) d += y_l[e]*yn_l[e];
      } else if (i == j+1){
        for (int e = lane; e < N; e += 64) d += v1_l[e]*yn_l[e];
      } else {
        const float* qi = Q + (size_t)i*N;
        for (int e = lane; e < N; e += 64) d += qi[e]*yn_l[e];
      }
      for (int o = 32; o > 0; o >>= 1) d += __shfl_down(d, o);
      if (lane == 0) cb2[i] = d;
    }
    __syncthreads();
    // ---- CGS pass B: subtract + norm ----
    float nn_p;
    {
      float a0 = 0.f, a1 = 0.f;
      for (int i = 0; i < j; i++){
        float2 q = *(const float2*)(Q + (size_t)i*N + e0);
        a0 += cb2[i]*q.x; a1 += cb2[i]*q.y;
      }
      a0 += cb2[j]*y_l[e0]   + cb2[j+1]*v1_l[e0];
      a1 += cb2[j]*y_l[e0+1] + cb2[j+1]*v1_l[e0+1];
      float v0 = yn_l[e0]   - a0;
      float v1v = yn_l[e0+1] - a1;
      yn_l[e0]   = v0;
      yn_l[e0+1] = v1v;
      nn_p = v0*v0 + v1v*v1v;
    }
    float nn = bsum16(nn_p, red);
    if (tid == 0){ alpha_l[j] = cb[j] + cb2[j]; beta_l[j] = sqrtf(nn); }
    // ---- normalize -> q_{j+1}; stage z; publish Q[j+1] ----
    {
      float rn = nn > 0.f ? rsqrtf(nn) : 0.f;
      float q0 = yn_l[e0]*rn, q1 = yn_l[e0+1]*rn;
      y_l[e0] = q0;   y_l[e0+1] = q1;
      z_l[e0] = dv_l[e0]*q0; z_l[e0+1] = dv_l[e0+1]*q1;
      *(float2*)(Q + (size_t)(j+1)*N + e0) = make_float2(q0, q1);
    }
    __syncthreads();
  }

  // ---- tridiagonal eig: 64-lane multisection (wave 0) + inverse iter ----
  for (int i = tid; i < KL; i += T1) ta[i] = (double)alpha_l[i];
  for (int i = tid; i < KL-1; i += T1){ double bb = (double)beta_l[i]; tb2[i] = bb*bb; }
  __syncthreads();
  if (wid == 0){
    double th[2];
    for (int k = 1; k <= 2; k++){
      double lo = -0.5, hi = 2.5;
      for (int r = 0; r < 5; r++){
        double xx = lo + (hi - lo)*(double)(lane + 1)/65.0;
        int c = 0; double q = 1.0;
        for (int i = 0; i < KL; i++){
          double t = ta[i] - xx - ((i > 0) ? tb2[i-1]/q : 0.0);
          if (t == 0.0) t = -1e-300;
          if (t < 0.0) c++;
          q = t;
        }
        unsigned long long m = __ballot(c >= k);
        if (m == 0ULL){
          lo = lo + (hi - lo)*(64.0/65.0);
        } else {
          int f = __ffsll((long long)m) - 1;
          double nhi = lo + (hi - lo)*(double)(f + 1)/65.0;
          double nlo = lo + (hi - lo)*(double)f/65.0;
          hi = nhi; lo = nlo;
        }
      }
      th[k-1] = 0.5*(lo + hi);
    }
    double theta = (th[0] < 0.25) ? th[1] : th[0];   // lambda1-ghost guard
    if (lane == 0){
      double d[KL], dl[KL], du[KL], du2[KL], xv[KL];
      int ip[KL];
      for (int i = 0; i < KL; i++) d[i] = ta[i] - theta;
      for (int i = 0; i < KL-1; i++){ double b = (double)beta_l[i]; dl[i] = b; du[i] = b; }
      for (int i = 0; i < KL-1; i++){
        if (fabs(d[i]) >= fabs(dl[i])){
          ip[i] = 0;
          if (d[i] == 0.0) d[i] = 1e-30;
          double f = dl[i]/d[i]; dl[i] = f; d[i+1] -= f*du[i];
          if (i < KL-2) du2[i] = 0.0;
        } else {
          double f = d[i]/dl[i];
          d[i] = dl[i]; dl[i] = f;
          double t = du[i]; du[i] = d[i+1]; d[i+1] = t - f*d[i+1];
          if (i < KL-2){ du2[i] = du[i+1]; du[i+1] = -f*du[i+1]; }
          ip[i] = 1;
        }
      }
      if (d[KL-1] == 0.0) d[KL-1] = 1e-30;
      for (int i = 0; i < KL; i++) xv[i] = (double)(wang(1000u + i) & 0xffffu)/65536.0 - 0.5;
      for (int it = 0; it < 4; it++){
        for (int i = 0; i < KL-1; i++){
          if (ip[i] == 0) xv[i+1] -= dl[i]*xv[i];
          else { double t = xv[i]; xv[i] = xv[i+1]; xv[i+1] = t - dl[i]*xv[i]; }
        }
        xv[KL-1] /= d[KL-1];
        xv[KL-2] = (xv[KL-2] - du[KL-2]*xv[KL-1])/d[KL-2];
        for (int i = KL-3; i >= 0; i--) xv[i] = (xv[i] - du[i]*xv[i+1] - du2[i]*xv[i+2])/d[i];
        double m = 0.0;
        for (int i = 0; i < KL; i++) m = fmax(m, fabs(xv[i]));
        if (m > 0.0) for (int i = 0; i < KL; i++) xv[i] /= m;
      }
      double nrm = 0.0;
      for (int i = 0; i < KL; i++) nrm += xv[i]*xv[i];
      nrm = sqrt(nrm);
      for (int i = 0; i < KL; i++) zl[i] = (float)(xv[i]/nrm);
    }
  }
  __syncthreads();
  // ---- Ritz: v2 = Q^T z (element-parallel, float2) ----
  float a0 = 0.f, a1 = 0.f;
  for (int i = 0; i < KL; i++){
    float2 q = *(const float2*)(Q + (size_t)i*N + e0);
    a0 += zl[i]*q.x; a1 += zl[i]*q.y;
  }
  yn_l[e0] = a0; yn_l[e0+1] = a1;          // v2 (unnormalized) in LDS
  // ---- stats: sumsq + max|.| + argmax ----
  float sq = bsum16(a0*a0 + a1*a1, red);
  {
    float av = fmaxf(fabsf(a0), fabsf(a1));
    for (int o = 32; o > 0; o >>= 1) av = fmaxf(av, __shfl_down(av, o));
    __syncthreads();
    if (lane == 0) red[wid] = av;
    if (tid == 0) idxs = N;
    __syncthreads();
    float m = red[0];
    for (int i = 1; i < 16; i++) m = fmaxf(m, red[i]);
    if (fabsf(a0) == m) atomicMin(&idxs, e0);
    if (fabsf(a1) == m) atomicMin(&idxs, e0+1);
    __syncthreads();
    if (tid == 0){
      float s = rsqrtf(sq);
      if (yn_l[idxs] < 0.f) s = -s;
      ssc[0] = SIGN2 * s;
    }
    __syncthreads();
  }
  // ---- write xc and output-2 ----
  {
    float sc = ssc[0];
    for (int k = 0; k < 2; k++){
      int i = e0 + k;
      float l1 = yn_l[i]*sc;
      float l0 = SIGN1*v1_l[i];
      float c0 = x[i*3+0], c1 = x[i*3+1], c2 = x[i*3+2];
      float* xr = xc + (size_t)i*5;
      xr[0]=c0; xr[1]=c1; xr[2]=c2; xr[3]=l0; xr[4]=l1;
      float* o = outbuf + (size_t)N*N + 1 + (size_t)i*5;
      o[0]=c0; o[1]=c1; o[2]=c2; o[3]=l0; o[4]=l1;
    }
  }
}

// ---------------- dense small linears ----------------
__global__ void k_lin(const float* in, const float* W, const float* b, float* out,
                      int Fin, int Fout, int act, int total){
  int t = blockIdx.x*TPB + threadIdx.x;
  if (t >= total) return;
  int i = t / Fout, f = t - i*Fout;
  float acc = b ? b[f] : 0.f;
  const float* ir = in + (size_t)i*Fin;
  for (int k2 = 0; k2 < Fin; k2++) acc += ir[k2]*W[k2*Fout + f];
  if (act) acc = fmaxf(acc, 0.f);
  out[t] = acc;
}
__global__ void k_lin3(const float* in,
                       const float* W0, const float* b0, float* o0,
                       const float* W1, const float* b1, float* o1,
                       const float* W2, const float* b2, float* o2){
  int t = blockIdx.x*TPB + threadIdx.x;
  if (t >= N*5) return;
  int i = t/5, f = t - i*5;
  const float* ir = in + (size_t)i*5;
  float a0 = b0[f], a1 = b1[f], a2 = b2[f];
  for (int c = 0; c < 5; c++){
    float h = ir[c];
    a0 += h*W0[c*5+f]; a1 += h*W1[c*5+f]; a2 += h*W2[c*5+f];
  }
  o0[t] = a0; o1[t] = a1; o2[t] = a2;
}
__global__ void k_alad(const float* hw, const float* as, const float* adp,
                       float* al, float* ad, int F){
  int i = blockIdx.x*TPB + threadIdx.x;
  if (i >= N) return;
  float s0 = 0.f, s1 = 0.f;
  const float* hr = hw + (size_t)i*F;
  for (int f = 0; f < F; f++){ float h = hr[f]; s0 += h*as[f]; s1 += h*adp[f]; }
  al[i] = s0; ad[i] = s1;
}

// ---------------- GAT row-gather (wave per row, no atomics) ----------------
__global__ __launch_bounds__(256) void k_gat_gather(
    const int* __restrict__ rowptr, const int* __restrict__ cols,
    const float* __restrict__ al, const float* __restrict__ ad,
    const float* __restrict__ hw, const float* __restrict__ bias,
    float* hout, int F, int act){
  int row = blockIdx.x*4 + (threadIdx.x >> 6);
  int lane = threadIdx.x & 63;
  int b0 = rowptr[row], b1 = rowptr[row+1];
  float adv = ad[row];
  float es = al[row] + adv; es = es >= 0.f ? es : 0.2f*es;
  float m = es;
  for (int p = b0 + lane; p < b1; p += 64){
    float e = al[cols[p]] + adv; e = e >= 0.f ? e : 0.2f*e;
    m = fmaxf(m, e);
  }
  for (int d = 1; d < 64; d <<= 1) m = fmaxf(m, __shfl_xor(m, d));
  float Z = 0.f;
  float accf[8];
  for (int f = 0; f < 8; f++) accf[f] = 0.f;
  for (int p = b0 + lane; p < b1; p += 64){
    int c = cols[p];
    float e = al[c] + adv; e = e >= 0.f ? e : 0.2f*e;
    float w = expf(e - m);
    Z += w;
    const float* hr = hw + (size_t)c*F;
    for (int f = 0; f < F; f++) accf[f] += w*hr[f];
  }
  if (lane == 0){
    float w = expf(es - m);
    Z += w;
    const float* hr = hw + (size_t)row*F;
    for (int f = 0; f < F; f++) accf[f] += w*hr[f];
  }
  for (int d = 1; d < 64; d <<= 1){
    Z += __shfl_xor(Z, d);
    for (int f = 0; f < F; f++) accf[f] += __shfl_xor(accf[f], d);
  }
  if (lane < F){
    float v = accf[lane]/(Z + 1e-16f) + bias[lane];
    if (act) v = fmaxf(v, 0.f);
    hout[(size_t)row*F + lane] = v;
  }
}

// ---------------- TransformerConv row-gather + root skip -------------------
__global__ __launch_bounds__(256) void k_tc_gather(
    const int* __restrict__ rowptr, const int* __restrict__ cols,
    const float* __restrict__ tq, const float* __restrict__ tk,
    const float* __restrict__ tv, const float* __restrict__ h3,
    const float* __restrict__ Wts, const float* __restrict__ bts, float* xt){
  int row = blockIdx.x*4 + (threadIdx.x >> 6);
  int lane = threadIdx.x & 63;
  int b0 = rowptr[row], b1 = rowptr[row+1];
  const float* qr = tq + (size_t)row*5;
  float q0=qr[0], q1=qr[1], q2=qr[2], q3=qr[3], q4=qr[4];
  const float* ks = tk + (size_t)row*5;
  float es = (q0*ks[0]+q1*ks[1]+q2*ks[2]+q3*ks[3]+q4*ks[4])*0.44721360f;
  float m = es;
  for (int p = b0 + lane; p < b1; p += 64){
    const float* kr = tk + (size_t)cols[p]*5;
    float e = (q0*kr[0]+q1*kr[1]+q2*kr[2]+q3*kr[3]+q4*kr[4])*0.44721360f;
    m = fmaxf(m, e);
  }
  for (int d = 1; d < 64; d <<= 1) m = fmaxf(m, __shfl_xor(m, d));
  float Z = 0.f;
  float accf[5];
  for (int f = 0; f < 5; f++) accf[f] = 0.f;
  for (int p = b0 + lane; p < b1; p += 64){
    int c = cols[p];
    const float* kr = tk + (size_t)c*5;
    float e = (q0*kr[0]+q1*kr[1]+q2*kr[2]+q3*kr[3]+q4*kr[4])*0.44721360f;
    float w = expf(e - m);
    Z += w;
    const float* vr = tv + (size_t)c*5;
    for (int f = 0; f < 5; f++) accf[f] += w*vr[f];
  }
  if (lane == 0){
    float w = expf(es - m);
    Z += w;
    const float* vr = tv + (size_t)row*5;
    for (int f = 0; f < 5; f++) accf[f] += w*vr[f];
  }
  for (int d = 1; d < 64; d <<= 1){
    Z += __shfl_xor(Z, d);
    for (int f = 0; f < 5; f++) accf[f] += __shfl_xor(accf[f], d);
  }
  if (lane < 5){
    const float* hr = h3 + (size_t)row*5;
    float skip = bts[lane];
    for (int k2 = 0; k2 < 5; k2++) skip += hr[k2]*Wts[k2*5 + lane];
    xt[(size_t)row*5 + lane] = accf[lane]/(Z + 1e-16f) + skip;
  }
}

// ---------------- GCN row-gathers ----------------
__global__ __launch_bounds__(256) void k_gcn16(
    const int* __restrict__ rowptr, const int* __restrict__ cols,
    const float* __restrict__ P16, const float* __restrict__ d2g,
    const float* __restrict__ bg1, float* z16){
  int row = blockIdx.x*4 + (threadIdx.x >> 6);
  int lane = threadIdx.x & 63;
  int b0 = rowptr[row], b1 = rowptr[row+1];
  float dr = d2g[row];
  float acc[16];
  for (int f = 0; f < 16; f++) acc[f] = 0.f;
  for (int p = b0 + lane; p < b1; p += 64){
    int c = cols[p];
    float w = d2g[c];
    const float* pr = P16 + (size_t)c*16;
    for (int f = 0; f < 16; f++) acc[f] += w*pr[f];
  }
  if (lane == 0){
    const float* pr = P16 + (size_t)row*16;
    for (int f = 0; f < 16; f++) acc[f] += dr*pr[f];
  }
  for (int d = 1; d < 64; d <<= 1)
    for (int f = 0; f < 16; f++) acc[f] += __shfl_xor(acc[f], d);
  if (lane < 16)
    z16[(size_t)row*16 + lane] = fmaxf(dr*acc[lane] + bg1[lane], 0.f);
}
__global__ __launch_bounds__(256) void k_gcn1(
    const int* __restrict__ rowptr, const int* __restrict__ cols,
    const float* __restrict__ p1, const float* __restrict__ d2g,
    const float* __restrict__ bg2, float* u, unsigned* mku, int* crit){
  int row = blockIdx.x*4 + (threadIdx.x >> 6);
  int lane = threadIdx.x & 63;
  if (blockIdx.x == 0 && threadIdx.x == 0) crit[0] = N;
  int b0 = rowptr[row], b1 = rowptr[row+1];
  float s = 0.f;
  for (int p = b0 + lane; p < b1; p += 64) s += d2g[cols[p]]*p1[cols[p]];
  if (lane == 0) s += d2g[row]*p1[row];
  for (int d = 1; d < 64; d <<= 1) s += __shfl_xor(s, d);
  float uv = d2g[row]*s + bg2[0];
  if (lane == 0){
    u[row] = uv;
    atomicMax(mku, fkey(uv));
  }
}
__global__ void k_crit(const float* u, const unsigned* mk, int* crit, float* bonus){
  int i = blockIdx.x*TPB + threadIdx.x;
  if (i == 0){
    float um = fkeyinv(mk[0]);
    bonus[0] = ((0.8f - um) < 0.2f) ? 10.f : 0.f;
  }
  if (i >= N) return;
  if (u[i] == fkeyinv(mk[0])) atomicMin(crit, i);
}

// ---------------- dense MHA ----------------
__global__ __launch_bounds__(256) void k_mha(const float* qb, const float* kb,
                                             const float* vb, float* av){
  __shared__ float s[N];
  __shared__ float sh[4];
  __shared__ float red[4];
  int i = blockIdx.x;
  const float* qr = qb + (size_t)i*5;
  float q0=qr[0], q1=qr[1], q2=qr[2], q3=qr[3], q4=qr[4];
  float lmax = -1e30f;
  for (int j = threadIdx.x; j < N; j += TPB){
    const float* kr = kb + (size_t)j*5;
    float sc = (q0*kr[0]+q1*kr[1]+q2*kr[2]+q3*kr[3]+q4*kr[4])*0.44721360f;
    s[j] = sc;
    lmax = fmaxf(lmax, sc);
  }
  for (int off = 32; off > 0; off >>= 1) lmax = fmaxf(lmax, __shfl_down(lmax, off));
  int lane = threadIdx.x & 63, w = threadIdx.x >> 6;
  if (lane == 0) red[w] = lmax;
  __syncthreads();
  float m = fmaxf(fmaxf(red[0], red[1]), fmaxf(red[2], red[3]));
  float Zp = 0.f, a0=0.f, a1=0.f, a2=0.f, a3=0.f, a4=0.f;
  for (int j = threadIdx.x; j < N; j += TPB){
    float p = expf(s[j] - m);
    const float* vr = vb + (size_t)j*5;
    Zp += p; a0 += p*vr[0]; a1 += p*vr[1]; a2 += p*vr[2]; a3 += p*vr[3]; a4 += p*vr[4];
  }
  float Z  = block_sum(Zp, sh);
  float A0 = block_sum(a0, sh);
  float A1 = block_sum(a1, sh);
  float A2 = block_sum(a2, sh);
  float A3 = block_sum(a3, sh);
  float A4 = block_sum(a4, sh);
  if (threadIdx.x == 0){
    float inv = 1.f/Z;
    float* o = av + (size_t)i*5;
    o[0]=A0*inv; o[1]=A1*inv; o[2]=A2*inv; o[3]=A3*inv; o[4]=A4*inv;
  }
}

// ---------------- final logits + value ----------------
__global__ __launch_bounds__(256) void k_logits(const float* hm, const float* W2,
    const float* b2, const float* mask, const float* Wc, const int* crit,
    const float* bonus, float* out, float* vacc){
  __shared__ float sh[4];
  int j = blockIdx.x*TPB + threadIdx.x;
  int i = blockIdx.y;
  const float* hr = hm + (size_t)i*64;
  float acc = b2[j];
  for (int c = 0; c < 64; c++) acc += hr[c]*W2[c*N + j];
  if (i == crit[0]) acc += bonus[0];
  out[(size_t)i*N + j] = acc*mask[j];
  float s = block_sum(acc*Wc[j], sh);
  if (threadIdx.x == 0) atomicAdd(vacc, s);
}
__global__ void k_value(const float* vacc, const float* bc, float* out){
  out[(size_t)N*N] = vacc[0]/(float)N + bc[0];
}

// ---------------------------------------------------------------------------
extern "C" void kernel_launch(void* const* d_in, const int* in_sizes, int n_in,
                              void* d_out, int out_size, void* d_ws, size_t ws_size,
                              hipStream_t stream){
  const float* x    = (const float*)d_in[0];
  const int*   ei   = (const int*)d_in[1];
  const float* mask = (const float*)d_in[2];
  const float* Wg1=(const float*)d_in[3];  const float* bg1=(const float*)d_in[4];
  const float* Wg2=(const float*)d_in[5];  const float* bg2=(const float*)d_in[6];
  const float* Wa1=(const float*)d_in[7];  const float* as1=(const float*)d_in[8];
  const float* ad1=(const float*)d_in[9];  const float* ba1=(const float*)d_in[10];
  const float* Wa2=(const float*)d_in[11]; const float* as2=(const float*)d_in[12];
  const float* ad2=(const float*)d_in[13]; const float* ba2=(const float*)d_in[14];
  const float* Wq=(const float*)d_in[15];  const float* bq=(const float*)d_in[16];
  const float* Wk=(const float*)d_in[17];  const float* bk=(const float*)d_in[18];
  const float* Wv=(const float*)d_in[19];  const float* bv=(const float*)d_in[20];
  const float* Wo=(const float*)d_in[21];  const float* bo=(const float*)d_in[22];
  const float* Wtq=(const float*)d_in[23]; const float* btq=(const float*)d_in[24];
  const float* Wtk=(const float*)d_in[25]; const float* btk=(const float*)d_in[26];
  const float* Wtv=(const float*)d_in[27]; const float* btv=(const float*)d_in[28];
  const float* Wts=(const float*)d_in[29]; const float* bts=(const float*)d_in[30];
  const float* W1=(const float*)d_in[31];  const float* b1=(const float*)d_in[32];
  const float* W2=(const float*)d_in[33];  const float* b2=(const float*)d_in[34];
  const float* Wc=(const float*)d_in[35];  const float* bc=(const float*)d_in[36];
  float* out = (float*)d_out;
  float* ws  = (float*)d_ws;

  // ---- ws layout (floats) ----
  float* deg  = ws;           float* dinv = ws + 2048;
  float* d2g  = ws + 4096;    float* v1   = ws + 6144;
  float* scal = ws + 12704;                        // 16 scalar slots
  unsigned* mku = (unsigned*)(scal + 8);
  int* crit = (int*)(scal + 10);
  float* al   = ws + 12848;   float* ad   = ws + 14896;
  float* h2   = ws + 21040;   float* qb   = ws + 31280;
  float* kb   = ws + 41520;   float* vb   = ws + 51760;
  float* h3   = ws + 62000;   float* tqb  = ws + 72240;
  float* tkb  = ws + 82480;   float* tvb  = ws + 92720;
  float* xt   = ws + 102960;  float* p1   = ws + 113200;
  float* u    = ws + 115248;  float* hm   = ws + 117296;   // 131072

  // ---- big scratch carved from d_out[0..N*N): consumed before k_logits ----
  float* Q    = out;                    // KL*N + N = 264192 (incl q_{KL})
  float* hw   = out + 266240;           // 16384
  float* h8   = out + 282624;           // 16384
  float* P16  = out + 299008;           // 32768
  float* z16  = out + 331776;           // 32768
  float* xc   = out + 364544;           // 10240
  int* rowptr = (int*)(out + 374784);   // 2049
  int* fill   = (int*)(out + 376840);   // 2048
  int* cols   = (int*)(out + 378888);   // 131072 -> ends 509960 << N*N

  // ================= setup =================
  k_zero<<<8, TPB, 0, stream>>>(deg, N);
  k_zero<<<1, TPB, 0, stream>>>(scal, 16);
  k_deg<<<NE/TPB, TPB, 0, stream>>>(ei, deg);
  k_nodeinit<<<8, TPB, 0, stream>>>(deg, dinv, d2g, v1);
  k_rowptr<<<1, TPB, 0, stream>>>(deg, rowptr, fill);
  k_csr<<<NE/TPB, TPB, 0, stream>>>(ei, fill, cols);

  // ================= Lanczos + teig + ritz + xc (ONE block) ================
  k_lanczos1<<<1, T1, 0, stream>>>(rowptr, cols, dinv, v1, x, Q, xc, out);

  const int gN5  = (N*5 + TPB-1)/TPB;
  const int gN8  = (N*8 + TPB-1)/TPB;
  const int gRow = N/4;

  // ================= GAT layer 1 (5 -> 8, relu) =================
  k_lin<<<gN8, TPB, 0, stream>>>(xc, Wa1, nullptr, hw, 5, 8, 0, N*8);
  k_alad<<<8, TPB, 0, stream>>>(hw, as1, ad1, al, ad, 8);
  k_gat_gather<<<gRow, TPB, 0, stream>>>(rowptr, cols, al, ad, hw, ba1, h8, 8, 1);

  // ================= GAT layer 2 (8 -> 5) =================
  k_lin<<<gN5, TPB, 0, stream>>>(h8, Wa2, nullptr, hw, 8, 5, 0, N*5);
  k_alad<<<8, TPB, 0, stream>>>(hw, as2, ad2, al, ad, 5);
  k_gat_gather<<<gRow, TPB, 0, stream>>>(rowptr, cols, al, ad, hw, ba2, h2, 5, 0);

  // ================= MultiheadAttention =================
  k_lin3<<<gN5, TPB, 0, stream>>>(h2, Wq, bq, qb, Wk, bk, kb, Wv, bv, vb);
  k_mha<<<N, TPB, 0, stream>>>(qb, kb, vb, hw);
  k_lin<<<gN5, TPB, 0, stream>>>(hw, Wo, bo, h3, 5, 5, 0, N*5);

  // ================= TransformerConv (fused skip) =================
  k_lin3<<<gN5, TPB, 0, stream>>>(h3, Wtq, btq, tqb, Wtk, btk, tkb, Wtv, btv, tvb);
  k_tc_gather<<<gRow, TPB, 0, stream>>>(rowptr, cols, tqb, tkb, tvb, h3, Wts, bts, xt);

  // ================= GCN uncertainty net =================
  k_lin<<<(N*16 + TPB-1)/TPB, TPB, 0, stream>>>(xt, Wg1, nullptr, P16, 5, 16, 0, N*16);
  k_gcn16<<<gRow, TPB, 0, stream>>>(rowptr, cols, P16, d2g, bg1, z16);
  k_lin<<<8, TPB, 0, stream>>>(z16, Wg2, nullptr, p1, 16, 1, 0, N);
  k_gcn1<<<gRow, TPB, 0, stream>>>(rowptr, cols, p1, d2g, bg2, u, mku, crit);
  k_crit<<<8, TPB, 0, stream>>>(u, mku, crit, scal + 5);

  // ================= MLP head + logits + value =================
  k_lin<<<(N*64 + TPB-1)/TPB, TPB, 0, stream>>>(xt, W1, b1, hm, 5, 64, 1, N*64);
  k_logits<<<dim3(8, N), TPB, 0, stream>>>(hm, W2, b2, mask, Wc, crit, scal + 5, out, scal + 6);
  k_value<<<1, 1, 0, stream>>>(scal + 6, bc, out);
}

// Round 11
// 2673.974 us; speedup vs baseline: 5.5611x; 5.5611x over previous
//
#include <hip/hip_runtime.h>
#include <math.h>

// ---------------------------------------------------------------------------
// observation_processing_network, gfx950.
// R5 6607us CSR gather.  R6 4832us slice-ownership (391 barriers x ~11us).
// R7 4692us fence-free -> no change (phase cost is structural LLC latency).
// R8 single-block 15ms -> REVERTED.  R9 compile fail (float4 asm input).
// R10: (1) KL 128->80 (Kaniel-Paige: sin(theta)~2e-4 at K=80); (2) cross-
//   block exchange via 8-byte agent-scope atomics (global_*_dwordx2 w/ sc
//   bits, compiler-tracked -- no asm).  Base = R7 (best verified 4692us).
// ---------------------------------------------------------------------------

#define N    2048
#define NE   131072
#define KL   80
#define TPB  256
#define NB   16
#define CH   (N/NB)      // 128 elements owned per block

#define SIGN1 -1.0f
#define SIGN2 -1.0f

// ---------------- device helpers ----------------
__device__ __forceinline__ unsigned fkey(float f){
  unsigned u = __float_as_uint(f);
  return (u & 0x80000000u) ? ~u : (u | 0x80000000u);
}
__device__ __forceinline__ float fkeyinv(unsigned k){
  unsigned u = (k & 0x80000000u) ? (k ^ 0x80000000u) : ~k;
  return __uint_as_float(u);
}
__device__ __forceinline__ unsigned wang(unsigned s){
  s = (s ^ 61u) ^ (s >> 16); s *= 9u; s ^= s >> 4; s *= 0x27d4eb2du; s ^= s >> 15;
  return s;
}
__device__ __forceinline__ float block_sum(float v, float* sh){
  __syncthreads();
  for (int off = 32; off > 0; off >>= 1) v += __shfl_down(v, off);
  int lane = threadIdx.x & 63, w = threadIdx.x >> 6;
  if (lane == 0) sh[w] = v;
  __syncthreads();
  return sh[0] + sh[1] + sh[2] + sh[3];
}

// ---- agent-scope (LLC-coherent) exchange primitives; 8B where possible ----
__device__ __forceinline__ float aloadf(const float* p){
  return __hip_atomic_load(p, __ATOMIC_RELAXED, __HIP_MEMORY_SCOPE_AGENT);
}
__device__ __forceinline__ void astoref(float* p, float v){
  __hip_atomic_store(p, v, __ATOMIC_RELAXED, __HIP_MEMORY_SCOPE_AGENT);
}
__device__ __forceinline__ unsigned aloadu(const unsigned* p){
  return __hip_atomic_load(p, __ATOMIC_RELAXED, __HIP_MEMORY_SCOPE_AGENT);
}
__device__ __forceinline__ int aloadi(const int* p){
  return __hip_atomic_load(p, __ATOMIC_RELAXED, __HIP_MEMORY_SCOPE_AGENT);
}
__device__ __forceinline__ void astorei(int* p, int v){
  __hip_atomic_store(p, v, __ATOMIC_RELAXED, __HIP_MEMORY_SCOPE_AGENT);
}
__device__ __forceinline__ float2 aload2(const float* p){
  unsigned long long v = __hip_atomic_load((const unsigned long long*)p,
                         __ATOMIC_RELAXED, __HIP_MEMORY_SCOPE_AGENT);
  return make_float2(__uint_as_float((unsigned)v),
                     __uint_as_float((unsigned)(v >> 32)));
}
__device__ __forceinline__ void astore2(float* p, float a, float b){
  unsigned long long v = ((unsigned long long)__float_as_uint(b) << 32)
                       | (unsigned long long)__float_as_uint(a);
  __hip_atomic_store((unsigned long long*)p, v,
                     __ATOMIC_RELAXED, __HIP_MEMORY_SCOPE_AGENT);
}

// Fence-free grid barrier (R7-validated). Monotone arrival counter;
// __syncthreads drains each wave's vmem before thread 0 arrives.
__device__ __forceinline__ void gbar(unsigned* cnt, unsigned* gen, unsigned* phase){
  __syncthreads();
  if (threadIdx.x == 0){
    unsigned p = ++(*phase);
    __atomic_signal_fence(__ATOMIC_SEQ_CST);
    __builtin_amdgcn_s_waitcnt(0);
    unsigned old = __hip_atomic_fetch_add(cnt, 1u, __ATOMIC_RELAXED, __HIP_MEMORY_SCOPE_AGENT);
    if (old == p*NB - 1u){
      __hip_atomic_store(gen, p, __ATOMIC_RELAXED, __HIP_MEMORY_SCOPE_AGENT);
    } else {
      while (__hip_atomic_load(gen, __ATOMIC_RELAXED, __HIP_MEMORY_SCOPE_AGENT) < p)
        __builtin_amdgcn_s_sleep(4);
    }
    __atomic_signal_fence(__ATOMIC_SEQ_CST);
  }
  __syncthreads();
}

// ---------------- small setup kernels ----------------
__global__ void k_zero(float* p, int n){ int i = blockIdx.x*TPB + threadIdx.x; if (i < n) p[i] = 0.f; }
__global__ void k_zerou(unsigned* p, int n){ int i = blockIdx.x*TPB + threadIdx.x; if (i < n) p[i] = 0u; }
__global__ void k_deg(const int* ei, float* deg){
  int e = blockIdx.x*TPB + threadIdx.x;
  if (e < NE) atomicAdd(&deg[ei[e]], 1.0f);
}
__global__ void k_nodeinit(const float* deg, float* dinv, float* d2g, float* v1){
  int i = blockIdx.x*TPB + threadIdx.x;
  if (i < N){
    float d = deg[i];
    dinv[i] = d > 0.f ? rsqrtf(d) : 0.f;
    d2g[i]  = rsqrtf(d + 1.f);
    v1[i]   = sqrtf(d / (float)NE);
  }
}
__global__ void k_rowptr(const float* deg, int* rowptr, int* fill){
  __shared__ int part[256];
  __shared__ int off[257];
  int t = threadIdx.x;
  int base = t*8;
  int local[8];
  int s = 0;
  for (int k = 0; k < 8; k++){ local[k] = s; s += (int)deg[base + k]; }
  part[t] = s;
  __syncthreads();
  if (t == 0){ off[0] = 0; for (int i = 0; i < 256; i++) off[i+1] = off[i] + part[i]; }
  __syncthreads();
  int o = off[t];
  for (int k = 0; k < 8; k++){ int v = o + local[k]; rowptr[base+k] = v; fill[base+k] = v; }
  if (t == 255) rowptr[N] = off[256];
}
__global__ void k_csr(const int* ei, int* fill, int* cols){
  int e = blockIdx.x*TPB + threadIdx.x;
  if (e < NE){
    int s = ei[e];
    int pos = atomicAdd(&fill[s], 1);
    cols[pos] = ei[NE + e];
  }
}

// ---------------- persistent Lanczos + teig + ritz + xc (one launch) -------
__global__ __launch_bounds__(256) void k_lanczos(
    const int* __restrict__ rowptr, const int* __restrict__ cols,
    const float* __restrict__ dinv, const float* __restrict__ v1,
    const float* __restrict__ x,
    float* Qsl, float* yG, float* parts, float* parts2, float* npart,
    float* alpha, float* beta, float* zsm, float* v2, float* xc,
    float* outbuf, float* scal, unsigned* mkv, int* v2i, unsigned* bar){
  __shared__ __align__(16) float ybuf[N];
  __shared__ __align__(16) float yl[CH];
  __shared__ float cb[KL+2], cb2[KL+2];
  __shared__ float npl[NB];
  __shared__ float zl[KL];
  __shared__ float sh[4];
  __shared__ unsigned mkl;
  __shared__ double ta[KL], tb2[KL];
  unsigned* cnt = bar;
  unsigned* gen = bar + 32;
  unsigned phase = 0;
  const int tid = threadIdx.x, blk = blockIdx.x;
  const int base = blk*CH;
  float* Qb = Qsl + (size_t)blk*KL*CH;
  float* ssq = scal + 3;

  // ---- I0: random start slice; v1-dot partial ----
  if (tid < CH){
    float r = (float)(wang(base + tid) & 0xffffffu) * (2.f/16777216.f) - 1.f;
    yl[tid] = r;
  }
  __syncthreads();
  {
    float p = (tid < CH) ? v1[base + tid]*yl[tid] : 0.f;
    float s = block_sum(p, sh);
    if (tid == 0) astoref(&parts[blk], s);
  }
  gbar(cnt, gen, &phase);
  // ---- I1: deflate v1; norm partial; publish y slice ----
  {
    if (tid < NB) npl[tid] = aloadf(&parts[tid]);
    __syncthreads();
    float c = 0.f;
    for (int b = 0; b < NB; b++) c += npl[b];
    float acc = 0.f;
    if (tid < CH){
      float v = yl[tid] - c*v1[base + tid];
      yl[tid] = v;
      acc = v*v;
    }
    __syncthreads();
    if (tid < CH/2) astore2(yG + base + 2*tid, yl[2*tid], yl[2*tid+1]);
    float s = block_sum(acc, sh);
    if (tid == 0) astoref(&npart[blk], s);
  }
  gbar(cnt, gen, &phase);

  for (int j = 0; j < KL; j++){
    // ---- P0: stage y (8B llc loads) + npart; rn; beta; SpMV; Q[j]; dots-a
    {
      for (int t = tid; t < N/2; t += TPB){
        float2 v = aload2(yG + 2*t);
        ybuf[2*t] = v.x; ybuf[2*t+1] = v.y;
      }
      if (tid < NB/2){
        float2 v = aload2(npart + 2*tid);
        npl[2*tid] = v.x; npl[2*tid+1] = v.y;
      }
    }
    __syncthreads();
    {
      float ss = 0.f;
      for (int b = 0; b < NB; b++) ss += npl[b];
      float rn = rsqrtf(ss);
      if (blk == 0 && tid == 0 && j > 0) beta[j-1] = sqrtf(ss);
      int r = tid >> 1;
      int half = tid & 1;
      int row = base + r;
      int b0 = rowptr[row], b1 = rowptr[row+1];
      float sg = 0.f;
      for (int p = b0 + half; p < b1; p += 2){
        int c = cols[p];
        sg += dinv[c]*ybuf[c];
      }
      sg += __shfl_down(sg, 1);
      if (half == 0){
        float q = rn*ybuf[row];
        Qb[(size_t)j*CH + r] = q;
        yl[r] = q - dinv[row]*rn*sg;
      }
    }
    __syncthreads();
    if (tid <= j+1){
      float d = 0.f;
      const float4* y4 = (const float4*)yl;
      if (tid <= j){
        const float4* q4 = (const float4*)(Qb + (size_t)tid*CH);
        for (int e = 0; e < CH/4; e++){
          float4 q = q4[e], yv = y4[e];
          d += q.x*yv.x + q.y*yv.y + q.z*yv.z + q.w*yv.w;
        }
      } else {
        const float4* v4 = (const float4*)(v1 + base);
        for (int e = 0; e < CH/4; e++){
          float4 q = v4[e], yv = y4[e];
          d += q.x*yv.x + q.y*yv.y + q.z*yv.z + q.w*yv.w;
        }
      }
      astoref(&parts[tid*NB + blk], d);
    }
    gbar(cnt, gen, &phase);
    // ---- P1: cb = rowsum(parts) via 8B loads; sub-a; dots-b ----
    if (tid <= j+1){
      const float* pr = parts + tid*NB;
      float s = 0.f;
      for (int b = 0; b < NB/2; b++){
        float2 v = aload2(pr + 2*b);
        s += v.x + v.y;
      }
      cb[tid] = s;
    }
    __syncthreads();
    {
      int e = tid >> 1, h = tid & 1;
      float a2 = 0.f;
      for (int i = h; i <= j+1; i += 2)
        a2 += cb[i] * ((i <= j) ? Qb[(size_t)i*CH + e] : v1[base + e]);
      a2 += __shfl_down(a2, 1);
      if (h == 0) yl[e] -= a2;
    }
    __syncthreads();
    if (tid <= j+1){
      float d = 0.f;
      const float4* y4 = (const float4*)yl;
      if (tid <= j){
        const float4* q4 = (const float4*)(Qb + (size_t)tid*CH);
        for (int e = 0; e < CH/4; e++){
          float4 q = q4[e], yv = y4[e];
          d += q.x*yv.x + q.y*yv.y + q.z*yv.z + q.w*yv.w;
        }
      } else {
        const float4* v4 = (const float4*)(v1 + base);
        for (int e = 0; e < CH/4; e++){
          float4 q = v4[e], yv = y4[e];
          d += q.x*yv.x + q.y*yv.y + q.z*yv.z + q.w*yv.w;
        }
      }
      astoref(&parts2[tid*NB + blk], d);
    }
    gbar(cnt, gen, &phase);
    // ---- P2: cb2 = rowsum(parts2); alpha; sub-b; norm; publish y (8B) ----
    if (tid <= j+1){
      const float* pr = parts2 + tid*NB;
      float s = 0.f;
      for (int b = 0; b < NB/2; b++){
        float2 v = aload2(pr + 2*b);
        s += v.x + v.y;
      }
      cb2[tid] = s;
    }
    __syncthreads();
    if (blk == 0 && tid == j) alpha[j] = cb[j] + cb2[j];
    float nv = 0.f;
    {
      int e = tid >> 1, h = tid & 1;
      float a2 = 0.f;
      for (int i = h; i <= j+1; i += 2)
        a2 += cb2[i] * ((i <= j) ? Qb[(size_t)i*CH + e] : v1[base + e]);
      a2 += __shfl_down(a2, 1);
      if (h == 0){
        float v = yl[e] - a2;
        yl[e] = v;
        nv = v*v;
      }
    }
    float s = block_sum(nv, sh);
    if (tid == 0) astoref(&npart[blk], s);
    if (tid < CH/2) astore2(yG + base + 2*tid, yl[2*tid], yl[2*tid+1]);
    gbar(cnt, gen, &phase);
  }

  // ---- tail: tridiagonal eig (block 0; alpha/beta blk0-local) ----
  const int wid = tid >> 6, lane = tid & 63;
  if (blk == 0){
    for (int i = tid; i < KL; i += TPB) ta[i] = (double)alpha[i];
    for (int i = tid; i < KL-1; i += TPB){ double bb = (double)beta[i]; tb2[i] = bb*bb; }
    __syncthreads();
    if (wid == 0){
      double th[2];
      for (int k = 1; k <= 2; k++){
        double lo = -0.5, hi = 2.5;
        for (int r = 0; r < 5; r++){
          double xx = lo + (hi - lo)*(double)(lane + 1)/65.0;
          int c = 0; double q = 1.0;
          for (int i = 0; i < KL; i++){
            double t = ta[i] - xx - ((i > 0) ? tb2[i-1]/q : 0.0);
            if (t == 0.0) t = -1e-300;
            if (t < 0.0) c++;
            q = t;
          }
          unsigned long long m = __ballot(c >= k);
          if (m == 0ULL){
            lo = lo + (hi - lo)*(64.0/65.0);
          } else {
            int f = __ffsll((long long)m) - 1;
            double nhi = lo + (hi - lo)*(double)(f + 1)/65.0;
            double nlo = lo + (hi - lo)*(double)f/65.0;
            hi = nhi; lo = nlo;
          }
        }
        th[k-1] = 0.5*(lo + hi);
      }
      double theta = (th[0] < 0.25) ? th[1] : th[0];
      if (lane == 0){
        double d[KL], dl[KL], du[KL], du2[KL], xv[KL];
        int ip[KL];
        for (int i = 0; i < KL; i++) d[i] = ta[i] - theta;
        for (int i = 0; i < KL-1; i++){ double b = (double)beta[i]; dl[i] = b; du[i] = b; }
        for (int i = 0; i < KL-1; i++){
          if (fabs(d[i]) >= fabs(dl[i])){
            ip[i] = 0;
            if (d[i] == 0.0) d[i] = 1e-30;
            double f = dl[i]/d[i]; dl[i] = f; d[i+1] -= f*du[i];
            if (i < KL-2) du2[i] = 0.0;
          } else {
            double f = d[i]/dl[i];
            d[i] = dl[i]; dl[i] = f;
            double t = du[i]; du[i] = d[i+1]; d[i+1] = t - f*d[i+1];
            if (i < KL-2){ du2[i] = du[i+1]; du[i+1] = -f*du[i+1]; }
            ip[i] = 1;
          }
        }
        if (d[KL-1] == 0.0) d[KL-1] = 1e-30;
        for (int i = 0; i < KL; i++) xv[i] = (double)(wang(1000u + i) & 0xffffu)/65536.0 - 0.5;
        for (int it = 0; it < 4; it++){
          for (int i = 0; i < KL-1; i++){
            if (ip[i] == 0) xv[i+1] -= dl[i]*xv[i];
            else { double t = xv[i]; xv[i] = xv[i+1]; xv[i+1] = t - dl[i]*xv[i]; }
          }
          xv[KL-1] /= d[KL-1];
          xv[KL-2] = (xv[KL-2] - du[KL-2]*xv[KL-1])/d[KL-2];
          for (int i = KL-3; i >= 0; i--) xv[i] = (xv[i] - du[i]*xv[i+1] - du2[i]*xv[i+2])/d[i];
          double m = 0.0;
          for (int i = 0; i < KL; i++) m = fmax(m, fabs(xv[i]));
          if (m > 0.0) for (int i = 0; i < KL; i++) xv[i] /= m;
        }
        double nrm = 0.0;
        for (int i = 0; i < KL; i++) nrm += xv[i]*xv[i];
        nrm = sqrt(nrm);
        for (int i = 0; i < KL; i++) astoref(&zsm[i], (float)(xv[i]/nrm));
      }
    }
  }
  gbar(cnt, gen, &phase);
  // ---- ritz + stats ----
  if (tid < KL) zl[tid] = aloadf(&zsm[tid]);
  __syncthreads();
  float a = 0.f;
  if (tid < CH){
    for (int i = 0; i < KL; i++) a += zl[i]*Qb[(size_t)i*CH + tid];
    astoref(&v2[base + tid], a);
  }
  {
    float sq = block_sum(a*a, sh);
    __syncthreads();
    float av = fabsf(a);
    for (int d2 = 1; d2 < 64; d2 <<= 1) av = fmaxf(av, __shfl_xor(av, d2));
    if ((tid & 63) == 0) sh[tid >> 6] = av;
    __syncthreads();
    if (tid == 0){
      float mb = fmaxf(fmaxf(sh[0], sh[1]), fmaxf(sh[2], sh[3]));
      atomicAdd(ssq, sq);
      atomicMax(mkv, fkey(mb));
      if (blk == 0) astorei(v2i, N);
    }
  }
  gbar(cnt, gen, &phase);
  // ---- idx of max |v2| ----
  if (tid == 0) mkl = aloadu(mkv);
  __syncthreads();
  if (tid < CH){
    float vv = aloadf(&v2[base + tid]);
    if (fkey(fabsf(vv)) == mkl) atomicMin(v2i, base + tid);
  }
  gbar(cnt, gen, &phase);
  // ---- sign/scale factor ----
  if (blk == 0 && tid == 0){
    float s = rsqrtf(aloadf(ssq));
    int ii = aloadi(v2i);
    if (aloadf(&v2[ii]) < 0.f) s = -s;
    astoref(&scal[4], SIGN2 * s);
  }
  gbar(cnt, gen, &phase);
  // ---- scale v2; write xc and output-2 ----
  if (tid < CH){
    int i = base + tid;
    float sc = aloadf(&scal[4]);
    float l1 = aloadf(&v2[i])*sc;
    float l0 = SIGN1*v1[i];
    float c0 = x[i*3+0], c1 = x[i*3+1], c2 = x[i*3+2];
    float* xr = xc + (size_t)i*5;
    xr[0]=c0; xr[1]=c1; xr[2]=c2; xr[3]=l0; xr[4]=l1;
    float* o = outbuf + (size_t)N*N + 1 + (size_t)i*5;
    o[0]=c0; o[1]=c1; o[2]=c2; o[3]=l0; o[4]=l1;
  }
}

// ---------------- dense small linears ----------------
__global__ void k_lin(const float* in, const float* W, const float* b, float* out,
                      int Fin, int Fout, int act, int total){
  int t = blockIdx.x*TPB + threadIdx.x;
  if (t >= total) return;
  int i = t / Fout, f = t - i*Fout;
  float acc = b ? b[f] : 0.f;
  const float* ir = in + (size_t)i*Fin;
  for (int k2 = 0; k2 < Fin; k2++) acc += ir[k2]*W[k2*Fout + f];
  if (act) acc = fmaxf(acc, 0.f);
  out[t] = acc;
}
__global__ void k_lin3(const float* in,
                       const float* W0, const float* b0, float* o0,
                       const float* W1, const float* b1, float* o1,
                       const float* W2, const float* b2, float* o2){
  int t = blockIdx.x*TPB + threadIdx.x;
  if (t >= N*5) return;
  int i = t/5, f = t - i*5;
  const float* ir = in + (size_t)i*5;
  float a0 = b0[f], a1 = b1[f], a2 = b2[f];
  for (int c = 0; c < 5; c++){
    float h = ir[c];
    a0 += h*W0[c*5+f]; a1 += h*W1[c*5+f]; a2 += h*W2[c*5+f];
  }
  o0[t] = a0; o1[t] = a1; o2[t] = a2;
}
__global__ void k_alad(const float* hw, const float* as, const float* adp,
                       float* al, float* ad, int F){
  int i = blockIdx.x*TPB + threadIdx.x;
  if (i >= N) return;
  float s0 = 0.f, s1 = 0.f;
  const float* hr = hw + (size_t)i*F;
  for (int f = 0; f < F; f++){ float h = hr[f]; s0 += h*as[f]; s1 += h*adp[f]; }
  al[i] = s0; ad[i] = s1;
}

// ---------------- GAT row-gather (wave per row, no atomics) ----------------
__global__ __launch_bounds__(256) void k_gat_gather(
    const int* __restrict__ rowptr, const int* __restrict__ cols,
    const float* __restrict__ al, const float* __restrict__ ad,
    const float* __restrict__ hw, const float* __restrict__ bias,
    float* hout, int F, int act){
  int row = blockIdx.x*4 + (threadIdx.x >> 6);
  int lane = threadIdx.x & 63;
  int b0 = rowptr[row], b1 = rowptr[row+1];
  float adv = ad[row];
  float es = al[row] + adv; es = es >= 0.f ? es : 0.2f*es;
  float m = es;
  for (int p = b0 + lane; p < b1; p += 64){
    float e = al[cols[p]] + adv; e = e >= 0.f ? e : 0.2f*e;
    m = fmaxf(m, e);
  }
  for (int d = 1; d < 64; d <<= 1) m = fmaxf(m, __shfl_xor(m, d));
  float Z = 0.f;
  float accf[8];
  for (int f = 0; f < 8; f++) accf[f] = 0.f;
  for (int p = b0 + lane; p < b1; p += 64){
    int c = cols[p];
    float e = al[c] + adv; e = e >= 0.f ? e : 0.2f*e;
    float w = expf(e - m);
    Z += w;
    const float* hr = hw + (size_t)c*F;
    for (int f = 0; f < F; f++) accf[f] += w*hr[f];
  }
  if (lane == 0){
    float w = expf(es - m);
    Z += w;
    const float* hr = hw + (size_t)row*F;
    for (int f = 0; f < F; f++) accf[f] += w*hr[f];
  }
  for (int d = 1; d < 64; d <<= 1){
    Z += __shfl_xor(Z, d);
    for (int f = 0; f < F; f++) accf[f] += __shfl_xor(accf[f], d);
  }
  if (lane < F){
    float v = accf[lane]/(Z + 1e-16f) + bias[lane];
    if (act) v = fmaxf(v, 0.f);
    hout[(size_t)row*F + lane] = v;
  }
}

// ---------------- TransformerConv row-gather + root skip -------------------
__global__ __launch_bounds__(256) void k_tc_gather(
    const int* __restrict__ rowptr, const int* __restrict__ cols,
    const float* __restrict__ tq, const float* __restrict__ tk,
    const float* __restrict__ tv, const float* __restrict__ h3,
    const float* __restrict__ Wts, const float* __restrict__ bts, float* xt){
  int row = blockIdx.x*4 + (threadIdx.x >> 6);
  int lane = threadIdx.x & 63;
  int b0 = rowptr[row], b1 = rowptr[row+1];
  const float* qr = tq + (size_t)row*5;
  float q0=qr[0], q1=qr[1], q2=qr[2], q3=qr[3], q4=qr[4];
  const float* ks = tk + (size_t)row*5;
  float es = (q0*ks[0]+q1*ks[1]+q2*ks[2]+q3*ks[3]+q4*ks[4])*0.44721360f;
  float m = es;
  for (int p = b0 + lane; p < b1; p += 64){
    const float* kr = tk + (size_t)cols[p]*5;
    float e = (q0*kr[0]+q1*kr[1]+q2*kr[2]+q3*kr[3]+q4*kr[4])*0.44721360f;
    m = fmaxf(m, e);
  }
  for (int d = 1; d < 64; d <<= 1) m = fmaxf(m, __shfl_xor(m, d));
  float Z = 0.f;
  float accf[5];
  for (int f = 0; f < 5; f++) accf[f] = 0.f;
  for (int p = b0 + lane; p < b1; p += 64){
    int c = cols[p];
    const float* kr = tk + (size_t)c*5;
    float e = (q0*kr[0]+q1*kr[1]+q2*kr[2]+q3*kr[3]+q4*kr[4])*0.44721360f;
    float w = expf(e - m);
    Z += w;
    const float* vr = tv + (size_t)c*5;
    for (int f = 0; f < 5; f++) accf[f] += w*vr[f];
  }
  if (lane == 0){
    float w = expf(es - m);
    Z += w;
    const float* vr = tv + (size_t)row*5;
    for (int f = 0; f < 5; f++) accf[f] += w*vr[f];
  }
  for (int d = 1; d < 64; d <<= 1){
    Z += __shfl_xor(Z, d);
    for (int f = 0; f < 5; f++) accf[f] += __shfl_xor(accf[f], d);
  }
  if (lane < 5){
    const float* hr = h3 + (size_t)row*5;
    float skip = bts[lane];
    for (int k2 = 0; k2 < 5; k2++) skip += hr[k2]*Wts[k2*5 + lane];
    xt[(size_t)row*5 + lane] = accf[lane]/(Z + 1e-16f) + skip;
  }
}

// ---------------- GCN row-gathers ----------------
__global__ __launch_bounds__(256) void k_gcn16(
    const int* __restrict__ rowptr, const int* __restrict__ cols,
    const float* __restrict__ P16, const float* __restrict__ d2g,
    const float* __restrict__ bg1, float* z16){
  int row = blockIdx.x*4 + (threadIdx.x >> 6);
  int lane = threadIdx.x & 63;
  int b0 = rowptr[row], b1 = rowptr[row+1];
  float dr = d2g[row];
  float acc[16];
  for (int f = 0; f < 16; f++) acc[f] = 0.f;
  for (int p = b0 + lane; p < b1; p += 64){
    int c = cols[p];
    float w = d2g[c];
    const float* pr = P16 + (size_t)c*16;
    for (int f = 0; f < 16; f++) acc[f] += w*pr[f];
  }
  if (lane == 0){
    const float* pr = P16 + (size_t)row*16;
    for (int f = 0; f < 16; f++) acc[f] += dr*pr[f];
  }
  for (int d = 1; d < 64; d <<= 1)
    for (int f = 0; f < 16; f++) acc[f] += __shfl_xor(acc[f], d);
  if (lane < 16)
    z16[(size_t)row*16 + lane] = fmaxf(dr*acc[lane] + bg1[lane], 0.f);
}
__global__ __launch_bounds__(256) void k_gcn1(
    const int* __restrict__ rowptr, const int* __restrict__ cols,
    const float* __restrict__ p1, const float* __restrict__ d2g,
    const float* __restrict__ bg2, float* u, unsigned* mku, int* crit){
  int row = blockIdx.x*4 + (threadIdx.x >> 6);
  int lane = threadIdx.x & 63;
  if (blockIdx.x == 0 && threadIdx.x == 0) crit[0] = N;
  int b0 = rowptr[row], b1 = rowptr[row+1];
  float s = 0.f;
  for (int p = b0 + lane; p < b1; p += 64) s += d2g[cols[p]]*p1[cols[p]];
  if (lane == 0) s += d2g[row]*p1[row];
  for (int d = 1; d < 64; d <<= 1) s += __shfl_xor(s, d);
  float uv = d2g[row]*s + bg2[0];
  if (lane == 0){
    u[row] = uv;
    atomicMax(mku, fkey(uv));
  }
}
__global__ void k_crit(const float* u, const unsigned* mk, int* crit, float* bonus){
  int i = blockIdx.x*TPB + threadIdx.x;
  if (i == 0){
    float um = fkeyinv(mk[0]);
    bonus[0] = ((0.8f - um) < 0.2f) ? 10.f : 0.f;
  }
  if (i >= N) return;
  if (u[i] == fkeyinv(mk[0])) atomicMin(crit, i);
}

// ---------------- dense MHA ----------------
__global__ __launch_bounds__(256) void k_mha(const float* qb, const float* kb,
                                             const float* vb, float* av){
  __shared__ float s[N];
  __shared__ float sh[4];
  __shared__ float red[4];
  int i = blockIdx.x;
  const float* qr = qb + (size_t)i*5;
  float q0=qr[0], q1=qr[1], q2=qr[2], q3=qr[3], q4=qr[4];
  float lmax = -1e30f;
  for (int j = threadIdx.x; j < N; j += TPB){
    const float* kr = kb + (size_t)j*5;
    float sc = (q0*kr[0]+q1*kr[1]+q2*kr[2]+q3*kr[3]+q4*kr[4])*0.44721360f;
    s[j] = sc;
    lmax = fmaxf(lmax, sc);
  }
  for (int off = 32; off > 0; off >>= 1) lmax = fmaxf(lmax, __shfl_down(lmax, off));
  int lane = threadIdx.x & 63, w = threadIdx.x >> 6;
  if (lane == 0) red[w] = lmax;
  __syncthreads();
  float m = fmaxf(fmaxf(red[0], red[1]), fmaxf(red[2], red[3]));
  float Zp = 0.f, a0=0.f, a1=0.f, a2=0.f, a3=0.f, a4=0.f;
  for (int j = threadIdx.x; j < N; j += TPB){
    float p = expf(s[j] - m);
    const float* vr = vb + (size_t)j*5;
    Zp += p; a0 += p*vr[0]; a1 += p*vr[1]; a2 += p*vr[2]; a3 += p*vr[3]; a4 += p*vr[4];
  }
  float Z  = block_sum(Zp, sh);
  float A0 = block_sum(a0, sh);
  float A1 = block_sum(a1, sh);
  float A2 = block_sum(a2, sh);
  float A3 = block_sum(a3, sh);
  float A4 = block_sum(a4, sh);
  if (threadIdx.x == 0){
    float inv = 1.f/Z;
    float* o = av + (size_t)i*5;
    o[0]=A0*inv; o[1]=A1*inv; o[2]=A2*inv; o[3]=A3*inv; o[4]=A4*inv;
  }
}

// ---------------- final logits + value ----------------
__global__ __launch_bounds__(256) void k_logits(const float* hm, const float* W2,
    const float* b2, const float* mask, const float* Wc, const int* crit,
    const float* bonus, float* out, float* vacc){
  __shared__ float sh[4];
  int j = blockIdx.x*TPB + threadIdx.x;
  int i = blockIdx.y;
  const float* hr = hm + (size_t)i*64;
  float acc = b2[j];
  for (int c = 0; c < 64; c++) acc += hr[c]*W2[c*N + j];
  if (i == crit[0]) acc += bonus[0];
  out[(size_t)i*N + j] = acc*mask[j];
  float s = block_sum(acc*Wc[j], sh);
  if (threadIdx.x == 0) atomicAdd(vacc, s);
}
__global__ void k_value(const float* vacc, const float* bc, float* out){
  out[(size_t)N*N] = vacc[0]/(float)N + bc[0];
}

// ---------------------------------------------------------------------------
extern "C" void kernel_launch(void* const* d_in, const int* in_sizes, int n_in,
                              void* d_out, int out_size, void* d_ws, size_t ws_size,
                              hipStream_t stream){
  const float* x    = (const float*)d_in[0];
  const int*   ei   = (const int*)d_in[1];
  const float* mask = (const float*)d_in[2];
  const float* Wg1=(const float*)d_in[3];  const float* bg1=(const float*)d_in[4];
  const float* Wg2=(const float*)d_in[5];  const float* bg2=(const float*)d_in[6];
  const float* Wa1=(const float*)d_in[7];  const float* as1=(const float*)d_in[8];
  const float* ad1=(const float*)d_in[9];  const float* ba1=(const float*)d_in[10];
  const float* Wa2=(const float*)d_in[11]; const float* as2=(const float*)d_in[12];
  const float* ad2=(const float*)d_in[13]; const float* ba2=(const float*)d_in[14];
  const float* Wq=(const float*)d_in[15];  const float* bq=(const float*)d_in[16];
  const float* Wk=(const float*)d_in[17];  const float* bk=(const float*)d_in[18];
  const float* Wv=(const float*)d_in[19];  const float* bv=(const float*)d_in[20];
  const float* Wo=(const float*)d_in[21];  const float* bo=(const float*)d_in[22];
  const float* Wtq=(const float*)d_in[23]; const float* btq=(const float*)d_in[24];
  const float* Wtk=(const float*)d_in[25]; const float* btk=(const float*)d_in[26];
  const float* Wtv=(const float*)d_in[27]; const float* btv=(const float*)d_in[28];
  const float* Wts=(const float*)d_in[29]; const float* bts=(const float*)d_in[30];
  const float* W1=(const float*)d_in[31];  const float* b1=(const float*)d_in[32];
  const float* W2=(const float*)d_in[33];  const float* b2=(const float*)d_in[34];
  const float* Wc=(const float*)d_in[35];  const float* bc=(const float*)d_in[36];
  float* out = (float*)d_out;
  float* ws  = (float*)d_ws;

  // ---- ws layout (floats) ----
  float* deg  = ws;           float* dinv = ws + 2048;
  float* d2g  = ws + 4096;    float* v1   = ws + 6144;
  float* y    = ws + 8192;    float* v2   = ws + 10240;
  float* alpha= ws + 12448;   float* beta = ws + 12576;
  float* scal = ws + 12704;                        // 16 scalar slots
  unsigned* mku = (unsigned*)(scal + 8);
  unsigned* mkv = (unsigned*)(scal + 9);
  int* crit = (int*)(scal + 10);
  int* v2i  = (int*)(scal + 11);
  float* zsm  = ws + 12720;                        // 128
  float* al   = ws + 12848;   float* ad   = ws + 14896;
  float* h2   = ws + 21040;   float* qb   = ws + 31280;
  float* kb   = ws + 41520;   float* vb   = ws + 51760;
  float* h3   = ws + 62000;   float* tqb  = ws + 72240;
  float* tkb  = ws + 82480;   float* tvb  = ws + 92720;
  float* xt   = ws + 102960;  float* p1   = ws + 113200;
  float* u    = ws + 115248;  float* hm   = ws + 117296;   // 131072

  // ---- big scratch carved from d_out[0..N*N): consumed before k_logits ----
  float* Qsl  = out;                    // NB*KL*CH = 163840
  float* hw   = out + 262144;           // 16384
  float* h8   = out + 278528;           // 16384
  float* P16  = out + 294912;           // 32768
  float* z16  = out + 327680;           // 32768
  float* xc   = out + 360448;           // 10240
  unsigned* bar = (unsigned*)(out + 370688);  // 64
  int* rowptr = (int*)(out + 370752);   // 2049
  int* fill   = (int*)(out + 372864);   // 2048
  int* cols   = (int*)(out + 374912);   // 131072 -> ends 505984
  float* parts  = out + 507904;         // (KL+2)*NB
  float* parts2 = out + 510080;         // (KL+2)*NB
  float* npart  = out + 512256;         // 16

  // ================= setup =================
  k_zero<<<8, TPB, 0, stream>>>(deg, N);
  k_zero<<<1, TPB, 0, stream>>>(scal, 16);
  k_zerou<<<1, TPB, 0, stream>>>(bar, 64);
  k_deg<<<NE/TPB, TPB, 0, stream>>>(ei, deg);
  k_nodeinit<<<8, TPB, 0, stream>>>(deg, dinv, d2g, v1);
  k_rowptr<<<1, TPB, 0, stream>>>(deg, rowptr, fill);
  k_csr<<<NE/TPB, TPB, 0, stream>>>(ei, fill, cols);

  // ================= Lanczos + teig + ritz + xc (one launch) ===============
  k_lanczos<<<NB, TPB, 0, stream>>>(rowptr, cols, dinv, v1, x, Qsl, y,
                                    parts, parts2, npart, alpha, beta, zsm,
                                    v2, xc, out, scal, mkv, v2i, bar);

  const int gN5  = (N*5 + TPB-1)/TPB;
  const int gN8  = (N*8 + TPB-1)/TPB;
  const int gRow = N/4;

  // ================= GAT layer 1 (5 -> 8, relu) =================
  k_lin<<<gN8, TPB, 0, stream>>>(xc, Wa1, nullptr, hw, 5, 8, 0, N*8);
  k_alad<<<8, TPB, 0, stream>>>(hw, as1, ad1, al, ad, 8);
  k_gat_gather<<<gRow, TPB, 0, stream>>>(rowptr, cols, al, ad, hw, ba1, h8, 8, 1);

  // ================= GAT layer 2 (8 -> 5) =================
  k_lin<<<gN5, TPB, 0, stream>>>(h8, Wa2, nullptr, hw, 8, 5, 0, N*5);
  k_alad<<<8, TPB, 0, stream>>>(hw, as2, ad2, al, ad, 5);
  k_gat_gather<<<gRow, TPB, 0, stream>>>(rowptr, cols, al, ad, hw, ba2, h2, 5, 0);

  // ================= MultiheadAttention =================
  k_lin3<<<gN5, TPB, 0, stream>>>(h2, Wq, bq, qb, Wk, bk, kb, Wv, bv, vb);
  k_mha<<<N, TPB, 0, stream>>>(qb, kb, vb, hw);
  k_lin<<<gN5, TPB, 0, stream>>>(hw, Wo, bo, h3, 5, 5, 0, N*5);

  // ================= TransformerConv (fused skip) =================
  k_lin3<<<gN5, TPB, 0, stream>>>(h3, Wtq, btq, tqb, Wtk, btk, tkb, Wtv, btv, tvb);
  k_tc_gather<<<gRow, TPB, 0, stream>>>(rowptr, cols, tqb, tkb, tvb, h3, Wts, bts, xt);

  // ================= GCN uncertainty net =================
  k_lin<<<(N*16 + TPB-1)/TPB, TPB, 0, stream>>>(xt, Wg1, nullptr, P16, 5, 16, 0, N*16);
  k_gcn16<<<gRow, TPB, 0, stream>>>(rowptr, cols, P16, d2g, bg1, z16);
  k_lin<<<8, TPB, 0, stream>>>(z16, Wg2, nullptr, p1, 16, 1, 0, N);
  k_gcn1<<<gRow, TPB, 0, stream>>>(rowptr, cols, p1, d2g, bg2, u, mku, crit);
  k_crit<<<8, TPB, 0, stream>>>(u, mku, crit, scal + 5);

  // ================= MLP head + logits + value =================
  k_lin<<<(N*64 + TPB-1)/TPB, TPB, 0, stream>>>(xt, W1, b1, hm, 5, 64, 1, N*64);
  k_logits<<<dim3(8, N), TPB, 0, stream>>>(hm, W2, b2, mask, Wc, crit, scal + 5, out, scal + 6);
  k_value<<<1, 1, 0, stream>>>(scal + 6, bc, out);
}

// Round 12
// 2071.858 us; speedup vs baseline: 7.1772x; 1.2906x over previous
//
#include <hip/hip_runtime.h>
#include <math.h>

// ---------------------------------------------------------------------------
// observation_processing_network, gfx950.
// R7 4692us (fence-free 16-block persistent Lanczos, 3 barriers/iter).
// R10 2674us: KL 128->80 + 8B agent-scope exchange; ~8.8us/phase structural.
// R11: KL 80->64 (Kaniel-Paige: ~5.8x error growth -> ~2e-3, still 8x under
//   threshold); GAT lin+alad+gather fused per layer; MHA-out+TC-qkv fused;
//   setup zeros fused; s_sleep 4->1.  3 barriers/iter is minimal for sliced
//   CGS2 (2 dot-reductions + 1 y-exchange per SpMV) -- not touched.
// ---------------------------------------------------------------------------

#define N    2048
#define NE   131072
#define KL   64
#define TPB  256
#define NB   16
#define CH   (N/NB)      // 128 elements owned per block

#define SIGN1 -1.0f
#define SIGN2 -1.0f

// ---------------- device helpers ----------------
__device__ __forceinline__ unsigned fkey(float f){
  unsigned u = __float_as_uint(f);
  return (u & 0x80000000u) ? ~u : (u | 0x80000000u);
}
__device__ __forceinline__ float fkeyinv(unsigned k){
  unsigned u = (k & 0x80000000u) ? (k ^ 0x80000000u) : ~k;
  return __uint_as_float(u);
}
__device__ __forceinline__ unsigned wang(unsigned s){
  s = (s ^ 61u) ^ (s >> 16); s *= 9u; s ^= s >> 4; s *= 0x27d4eb2du; s ^= s >> 15;
  return s;
}
__device__ __forceinline__ float block_sum(float v, float* sh){
  __syncthreads();
  for (int off = 32; off > 0; off >>= 1) v += __shfl_down(v, off);
  int lane = threadIdx.x & 63, w = threadIdx.x >> 6;
  if (lane == 0) sh[w] = v;
  __syncthreads();
  return sh[0] + sh[1] + sh[2] + sh[3];
}

// ---- agent-scope (LLC-coherent) exchange primitives; 8B where possible ----
__device__ __forceinline__ float aloadf(const float* p){
  return __hip_atomic_load(p, __ATOMIC_RELAXED, __HIP_MEMORY_SCOPE_AGENT);
}
__device__ __forceinline__ void astoref(float* p, float v){
  __hip_atomic_store(p, v, __ATOMIC_RELAXED, __HIP_MEMORY_SCOPE_AGENT);
}
__device__ __forceinline__ unsigned aloadu(const unsigned* p){
  return __hip_atomic_load(p, __ATOMIC_RELAXED, __HIP_MEMORY_SCOPE_AGENT);
}
__device__ __forceinline__ int aloadi(const int* p){
  return __hip_atomic_load(p, __ATOMIC_RELAXED, __HIP_MEMORY_SCOPE_AGENT);
}
__device__ __forceinline__ void astorei(int* p, int v){
  __hip_atomic_store(p, v, __ATOMIC_RELAXED, __HIP_MEMORY_SCOPE_AGENT);
}
__device__ __forceinline__ float2 aload2(const float* p){
  unsigned long long v = __hip_atomic_load((const unsigned long long*)p,
                         __ATOMIC_RELAXED, __HIP_MEMORY_SCOPE_AGENT);
  return make_float2(__uint_as_float((unsigned)v),
                     __uint_as_float((unsigned)(v >> 32)));
}
__device__ __forceinline__ void astore2(float* p, float a, float b){
  unsigned long long v = ((unsigned long long)__float_as_uint(b) << 32)
                       | (unsigned long long)__float_as_uint(a);
  __hip_atomic_store((unsigned long long*)p, v,
                     __ATOMIC_RELAXED, __HIP_MEMORY_SCOPE_AGENT);
}

// Fence-free grid barrier (R7-validated). Monotone arrival counter.
__device__ __forceinline__ void gbar(unsigned* cnt, unsigned* gen, unsigned* phase){
  __syncthreads();
  if (threadIdx.x == 0){
    unsigned p = ++(*phase);
    __atomic_signal_fence(__ATOMIC_SEQ_CST);
    __builtin_amdgcn_s_waitcnt(0);
    unsigned old = __hip_atomic_fetch_add(cnt, 1u, __ATOMIC_RELAXED, __HIP_MEMORY_SCOPE_AGENT);
    if (old == p*NB - 1u){
      __hip_atomic_store(gen, p, __ATOMIC_RELAXED, __HIP_MEMORY_SCOPE_AGENT);
    } else {
      while (__hip_atomic_load(gen, __ATOMIC_RELAXED, __HIP_MEMORY_SCOPE_AGENT) < p)
        __builtin_amdgcn_s_sleep(1);
    }
    __atomic_signal_fence(__ATOMIC_SEQ_CST);
  }
  __syncthreads();
}

// ---------------- setup kernels ----------------
__global__ void k_init(float* deg, float* scal, unsigned* bar){
  int i = blockIdx.x*TPB + threadIdx.x;
  if (i < N) deg[i] = 0.f;
  if (i < 16) scal[i] = 0.f;
  if (i < 64) bar[i] = 0u;
}
__global__ void k_deg(const int* ei, float* deg){
  int e = blockIdx.x*TPB + threadIdx.x;
  if (e < NE) atomicAdd(&deg[ei[e]], 1.0f);
}
__global__ void k_nodeinit(const float* deg, float* dinv, float* d2g, float* v1){
  int i = blockIdx.x*TPB + threadIdx.x;
  if (i < N){
    float d = deg[i];
    dinv[i] = d > 0.f ? rsqrtf(d) : 0.f;
    d2g[i]  = rsqrtf(d + 1.f);
    v1[i]   = sqrtf(d / (float)NE);
  }
}
__global__ void k_rowptr(const float* deg, int* rowptr, int* fill){
  __shared__ int part[256];
  __shared__ int off[257];
  int t = threadIdx.x;
  int base = t*8;
  int local[8];
  int s = 0;
  for (int k = 0; k < 8; k++){ local[k] = s; s += (int)deg[base + k]; }
  part[t] = s;
  __syncthreads();
  if (t == 0){ off[0] = 0; for (int i = 0; i < 256; i++) off[i+1] = off[i] + part[i]; }
  __syncthreads();
  int o = off[t];
  for (int k = 0; k < 8; k++){ int v = o + local[k]; rowptr[base+k] = v; fill[base+k] = v; }
  if (t == 255) rowptr[N] = off[256];
}
__global__ void k_csr(const int* ei, int* fill, int* cols){
  int e = blockIdx.x*TPB + threadIdx.x;
  if (e < NE){
    int s = ei[e];
    int pos = atomicAdd(&fill[s], 1);
    cols[pos] = ei[NE + e];
  }
}

// ---------------- persistent Lanczos + teig + ritz + xc (one launch) -------
__global__ __launch_bounds__(256) void k_lanczos(
    const int* __restrict__ rowptr, const int* __restrict__ cols,
    const float* __restrict__ dinv, const float* __restrict__ v1,
    const float* __restrict__ x,
    float* Qsl, float* yG, float* parts, float* parts2, float* npart,
    float* alpha, float* beta, float* zsm, float* v2, float* xc,
    float* outbuf, float* scal, unsigned* mkv, int* v2i, unsigned* bar){
  __shared__ __align__(16) float ybuf[N];
  __shared__ __align__(16) float yl[CH];
  __shared__ float cb[KL+2], cb2[KL+2];
  __shared__ float npl[NB];
  __shared__ float zl[KL];
  __shared__ float sh[4];
  __shared__ unsigned mkl;
  __shared__ double ta[KL], tb2[KL];
  unsigned* cnt = bar;
  unsigned* gen = bar + 32;
  unsigned phase = 0;
  const int tid = threadIdx.x, blk = blockIdx.x;
  const int base = blk*CH;
  float* Qb = Qsl + (size_t)blk*KL*CH;
  float* ssq = scal + 3;

  // ---- I0: random start slice; v1-dot partial ----
  if (tid < CH){
    float r = (float)(wang(base + tid) & 0xffffffu) * (2.f/16777216.f) - 1.f;
    yl[tid] = r;
  }
  __syncthreads();
  {
    float p = (tid < CH) ? v1[base + tid]*yl[tid] : 0.f;
    float s = block_sum(p, sh);
    if (tid == 0) astoref(&parts[blk], s);
  }
  gbar(cnt, gen, &phase);
  // ---- I1: deflate v1; norm partial; publish y slice ----
  {
    if (tid < NB) npl[tid] = aloadf(&parts[tid]);
    __syncthreads();
    float c = 0.f;
    for (int b = 0; b < NB; b++) c += npl[b];
    float acc = 0.f;
    if (tid < CH){
      float v = yl[tid] - c*v1[base + tid];
      yl[tid] = v;
      acc = v*v;
    }
    __syncthreads();
    if (tid < CH/2) astore2(yG + base + 2*tid, yl[2*tid], yl[2*tid+1]);
    float s = block_sum(acc, sh);
    if (tid == 0) astoref(&npart[blk], s);
  }
  gbar(cnt, gen, &phase);

  for (int j = 0; j < KL; j++){
    // ---- P0: stage y (8B llc loads) + npart; rn; beta; SpMV; Q[j]; dots-a
    {
      for (int t = tid; t < N/2; t += TPB){
        float2 v = aload2(yG + 2*t);
        ybuf[2*t] = v.x; ybuf[2*t+1] = v.y;
      }
      if (tid < NB/2){
        float2 v = aload2(npart + 2*tid);
        npl[2*tid] = v.x; npl[2*tid+1] = v.y;
      }
    }
    __syncthreads();
    {
      float ss = 0.f;
      for (int b = 0; b < NB; b++) ss += npl[b];
      float rn = rsqrtf(ss);
      if (blk == 0 && tid == 0 && j > 0) beta[j-1] = sqrtf(ss);
      int r = tid >> 1;
      int half = tid & 1;
      int row = base + r;
      int b0 = rowptr[row], b1 = rowptr[row+1];
      float sg = 0.f;
      for (int p = b0 + half; p < b1; p += 2){
        int c = cols[p];
        sg += dinv[c]*ybuf[c];
      }
      sg += __shfl_down(sg, 1);
      if (half == 0){
        float q = rn*ybuf[row];
        Qb[(size_t)j*CH + r] = q;
        yl[r] = q - dinv[row]*rn*sg;
      }
    }
    __syncthreads();
    if (tid <= j+1){
      float d = 0.f;
      const float4* y4 = (const float4*)yl;
      if (tid <= j){
        const float4* q4 = (const float4*)(Qb + (size_t)tid*CH);
        for (int e = 0; e < CH/4; e++){
          float4 q = q4[e], yv = y4[e];
          d += q.x*yv.x + q.y*yv.y + q.z*yv.z + q.w*yv.w;
        }
      } else {
        const float4* v4 = (const float4*)(v1 + base);
        for (int e = 0; e < CH/4; e++){
          float4 q = v4[e], yv = y4[e];
          d += q.x*yv.x + q.y*yv.y + q.z*yv.z + q.w*yv.w;
        }
      }
      astoref(&parts[tid*NB + blk], d);
    }
    gbar(cnt, gen, &phase);
    // ---- P1: cb = rowsum(parts) via 8B loads; sub-a; dots-b ----
    if (tid <= j+1){
      const float* pr = parts + tid*NB;
      float s = 0.f;
      for (int b = 0; b < NB/2; b++){
        float2 v = aload2(pr + 2*b);
        s += v.x + v.y;
      }
      cb[tid] = s;
    }
    __syncthreads();
    {
      int e = tid >> 1, h = tid & 1;
      float a2 = 0.f;
      for (int i = h; i <= j+1; i += 2)
        a2 += cb[i] * ((i <= j) ? Qb[(size_t)i*CH + e] : v1[base + e]);
      a2 += __shfl_down(a2, 1);
      if (h == 0) yl[e] -= a2;
    }
    __syncthreads();
    if (tid <= j+1){
      float d = 0.f;
      const float4* y4 = (const float4*)yl;
      if (tid <= j){
        const float4* q4 = (const float4*)(Qb + (size_t)tid*CH);
        for (int e = 0; e < CH/4; e++){
          float4 q = q4[e], yv = y4[e];
          d += q.x*yv.x + q.y*yv.y + q.z*yv.z + q.w*yv.w;
        }
      } else {
        const float4* v4 = (const float4*)(v1 + base);
        for (int e = 0; e < CH/4; e++){
          float4 q = v4[e], yv = y4[e];
          d += q.x*yv.x + q.y*yv.y + q.z*yv.z + q.w*yv.w;
        }
      }
      astoref(&parts2[tid*NB + blk], d);
    }
    gbar(cnt, gen, &phase);
    // ---- P2: cb2 = rowsum(parts2); alpha; sub-b; norm; publish y (8B) ----
    if (tid <= j+1){
      const float* pr = parts2 + tid*NB;
      float s = 0.f;
      for (int b = 0; b < NB/2; b++){
        float2 v = aload2(pr + 2*b);
        s += v.x + v.y;
      }
      cb2[tid] = s;
    }
    __syncthreads();
    if (blk == 0 && tid == j) alpha[j] = cb[j] + cb2[j];
    float nv = 0.f;
    {
      int e = tid >> 1, h = tid & 1;
      float a2 = 0.f;
      for (int i = h; i <= j+1; i += 2)
        a2 += cb2[i] * ((i <= j) ? Qb[(size_t)i*CH + e] : v1[base + e]);
      a2 += __shfl_down(a2, 1);
      if (h == 0){
        float v = yl[e] - a2;
        yl[e] = v;
        nv = v*v;
      }
    }
    float s = block_sum(nv, sh);
    if (tid == 0) astoref(&npart[blk], s);
    if (tid < CH/2) astore2(yG + base + 2*tid, yl[2*tid], yl[2*tid+1]);
    gbar(cnt, gen, &phase);
  }

  // ---- tail: tridiagonal eig (block 0; alpha/beta blk0-local) ----
  const int wid = tid >> 6, lane = tid & 63;
  if (blk == 0){
    for (int i = tid; i < KL; i += TPB) ta[i] = (double)alpha[i];
    for (int i = tid; i < KL-1; i += TPB){ double bb = (double)beta[i]; tb2[i] = bb*bb; }
    __syncthreads();
    if (wid == 0){
      double th[2];
      for (int k = 1; k <= 2; k++){
        double lo = -0.5, hi = 2.5;
        for (int r = 0; r < 5; r++){
          double xx = lo + (hi - lo)*(double)(lane + 1)/65.0;
          int c = 0; double q = 1.0;
          for (int i = 0; i < KL; i++){
            double t = ta[i] - xx - ((i > 0) ? tb2[i-1]/q : 0.0);
            if (t == 0.0) t = -1e-300;
            if (t < 0.0) c++;
            q = t;
          }
          unsigned long long m = __ballot(c >= k);
          if (m == 0ULL){
            lo = lo + (hi - lo)*(64.0/65.0);
          } else {
            int f = __ffsll((long long)m) - 1;
            double nhi = lo + (hi - lo)*(double)(f + 1)/65.0;
            double nlo = lo + (hi - lo)*(double)f/65.0;
            hi = nhi; lo = nlo;
          }
        }
        th[k-1] = 0.5*(lo + hi);
      }
      double theta = (th[0] < 0.25) ? th[1] : th[0];
      if (lane == 0){
        double d[KL], dl[KL], du[KL], du2[KL], xv[KL];
        int ip[KL];
        for (int i = 0; i < KL; i++) d[i] = ta[i] - theta;
        for (int i = 0; i < KL-1; i++){ double b = (double)beta[i]; dl[i] = b; du[i] = b; }
        for (int i = 0; i < KL-1; i++){
          if (fabs(d[i]) >= fabs(dl[i])){
            ip[i] = 0;
            if (d[i] == 0.0) d[i] = 1e-30;
            double f = dl[i]/d[i]; dl[i] = f; d[i+1] -= f*du[i];
            if (i < KL-2) du2[i] = 0.0;
          } else {
            double f = d[i]/dl[i];
            d[i] = dl[i]; dl[i] = f;
            double t = du[i]; du[i] = d[i+1]; d[i+1] = t - f*d[i+1];
            if (i < KL-2){ du2[i] = du[i+1]; du[i+1] = -f*du[i+1]; }
            ip[i] = 1;
          }
        }
        if (d[KL-1] == 0.0) d[KL-1] = 1e-30;
        for (int i = 0; i < KL; i++) xv[i] = (double)(wang(1000u + i) & 0xffffu)/65536.0 - 0.5;
        for (int it = 0; it < 4; it++){
          for (int i = 0; i < KL-1; i++){
            if (ip[i] == 0) xv[i+1] -= dl[i]*xv[i];
            else { double t = xv[i]; xv[i] = xv[i+1]; xv[i+1] = t - dl[i]*xv[i]; }
          }
          xv[KL-1] /= d[KL-1];
          xv[KL-2] = (xv[KL-2] - du[KL-2]*xv[KL-1])/d[KL-2];
          for (int i = KL-3; i >= 0; i--) xv[i] = (xv[i] - du[i]*xv[i+1] - du2[i]*xv[i+2])/d[i];
          double m = 0.0;
          for (int i = 0; i < KL; i++) m = fmax(m, fabs(xv[i]));
          if (m > 0.0) for (int i = 0; i < KL; i++) xv[i] /= m;
        }
        double nrm = 0.0;
        for (int i = 0; i < KL; i++) nrm += xv[i]*xv[i];
        nrm = sqrt(nrm);
        for (int i = 0; i < KL; i++) astoref(&zsm[i], (float)(xv[i]/nrm));
      }
    }
  }
  gbar(cnt, gen, &phase);
  // ---- ritz + stats ----
  if (tid < KL) zl[tid] = aloadf(&zsm[tid]);
  __syncthreads();
  float a = 0.f;
  if (tid < CH){
    for (int i = 0; i < KL; i++) a += zl[i]*Qb[(size_t)i*CH + tid];
    astoref(&v2[base + tid], a);
  }
  {
    float sq = block_sum(a*a, sh);
    __syncthreads();
    float av = fabsf(a);
    for (int d2 = 1; d2 < 64; d2 <<= 1) av = fmaxf(av, __shfl_xor(av, d2));
    if ((tid & 63) == 0) sh[tid >> 6] = av;
    __syncthreads();
    if (tid == 0){
      float mb = fmaxf(fmaxf(sh[0], sh[1]), fmaxf(sh[2], sh[3]));
      atomicAdd(ssq, sq);
      atomicMax(mkv, fkey(mb));
      if (blk == 0) astorei(v2i, N);
    }
  }
  gbar(cnt, gen, &phase);
  // ---- idx of max |v2| ----
  if (tid == 0) mkl = aloadu(mkv);
  __syncthreads();
  if (tid < CH){
    float vv = aloadf(&v2[base + tid]);
    if (fkey(fabsf(vv)) == mkl) atomicMin(v2i, base + tid);
  }
  gbar(cnt, gen, &phase);
  // ---- sign/scale factor ----
  if (blk == 0 && tid == 0){
    float s = rsqrtf(aloadf(ssq));
    int ii = aloadi(v2i);
    if (aloadf(&v2[ii]) < 0.f) s = -s;
    astoref(&scal[4], SIGN2 * s);
  }
  gbar(cnt, gen, &phase);
  // ---- scale v2; write xc and output-2 ----
  if (tid < CH){
    int i = base + tid;
    float sc = aloadf(&scal[4]);
    float l1 = aloadf(&v2[i])*sc;
    float l0 = SIGN1*v1[i];
    float c0 = x[i*3+0], c1 = x[i*3+1], c2 = x[i*3+2];
    float* xr = xc + (size_t)i*5;
    xr[0]=c0; xr[1]=c1; xr[2]=c2; xr[3]=l0; xr[4]=l1;
    float* o = outbuf + (size_t)N*N + 1 + (size_t)i*5;
    o[0]=c0; o[1]=c1; o[2]=c2; o[3]=l0; o[4]=l1;
  }
}

// ---------------- dense small linears ----------------
__global__ void k_lin(const float* in, const float* W, const float* b, float* out,
                      int Fin, int Fout, int act, int total){
  int t = blockIdx.x*TPB + threadIdx.x;
  if (t >= total) return;
  int i = t / Fout, f = t - i*Fout;
  float acc = b ? b[f] : 0.f;
  const float* ir = in + (size_t)i*Fin;
  for (int k2 = 0; k2 < Fin; k2++) acc += ir[k2]*W[k2*Fout + f];
  if (act) acc = fmaxf(acc, 0.f);
  out[t] = acc;
}
__global__ void k_lin3(const float* in,
                       const float* W0, const float* b0, float* o0,
                       const float* W1, const float* b1, float* o1,
                       const float* W2, const float* b2, float* o2){
  int t = blockIdx.x*TPB + threadIdx.x;
  if (t >= N*5) return;
  int i = t/5, f = t - i*5;
  const float* ir = in + (size_t)i*5;
  float a0 = b0[f], a1 = b1[f], a2 = b2[f];
  for (int c = 0; c < 5; c++){
    float h = ir[c];
    a0 += h*W0[c*5+f]; a1 += h*W1[c*5+f]; a2 += h*W2[c*5+f];
  }
  o0[t] = a0; o1[t] = a1; o2[t] = a2;
}
// fused: h3 = attnout@Wo+bo, then tq/tk/tv = h3@Wt*+bt*  (one thread/node)
__global__ void k_h3tc(const float* att, const float* Wo, const float* bo,
                       const float* Wtq, const float* btq,
                       const float* Wtk, const float* btk,
                       const float* Wtv, const float* btv,
                       float* h3, float* tq, float* tk, float* tv){
  int i = blockIdx.x*TPB + threadIdx.x;
  if (i >= N) return;
  const float* ar = att + (size_t)i*5;
  float h[5];
  for (int f = 0; f < 5; f++){
    float acc = bo[f];
    for (int k = 0; k < 5; k++) acc += ar[k]*Wo[k*5+f];
    h[f] = acc;
  }
  float* hr = h3 + (size_t)i*5;
  float* qr = tq + (size_t)i*5;
  float* kr = tk + (size_t)i*5;
  float* vr = tv + (size_t)i*5;
  for (int f = 0; f < 5; f++){
    float aq = btq[f], ak = btk[f], av = btv[f];
    for (int k = 0; k < 5; k++){
      float hk = h[k];
      aq += hk*Wtq[k*5+f]; ak += hk*Wtk[k*5+f]; av += hk*Wtv[k*5+f];
    }
    hr[f] = h[f]; qr[f] = aq; kr[f] = ak; vr[f] = av;
  }
}

// ---------------- fused GAT layer: lin + attention scores + gather ---------
// wave per row; hw computed on the fly (Fin,F <= 8)
__global__ __launch_bounds__(256) void k_gat_fused(
    const int* __restrict__ rowptr, const int* __restrict__ cols,
    const float* __restrict__ in, const float* __restrict__ W,
    const float* __restrict__ as, const float* __restrict__ adp,
    const float* __restrict__ bias, float* hout, int Fin, int F, int act){
  int row = blockIdx.x*4 + (threadIdx.x >> 6);
  int lane = threadIdx.x & 63;
  int b0 = rowptr[row], b1 = rowptr[row+1];
  // hw_row (redundant per lane; <= 64 mults)
  float hwr[8];
  {
    const float* ir = in + (size_t)row*Fin;
    for (int f = 0; f < F; f++){
      float acc = 0.f;
      for (int k = 0; k < Fin; k++) acc += ir[k]*W[k*F+f];
      hwr[f] = acc;
    }
  }
  float adv = 0.f, alr = 0.f;
  for (int f = 0; f < F; f++){ adv += hwr[f]*adp[f]; alr += hwr[f]*as[f]; }
  float es = alr + adv; es = es >= 0.f ? es : 0.2f*es;
  // pass 1: max
  float m = es;
  for (int p = b0 + lane; p < b1; p += 64){
    const float* ic = in + (size_t)cols[p]*Fin;
    float al = 0.f;
    for (int f = 0; f < F; f++){
      float acc = 0.f;
      for (int k = 0; k < Fin; k++) acc += ic[k]*W[k*F+f];
      al += acc*as[f];
    }
    float e = al + adv; e = e >= 0.f ? e : 0.2f*e;
    m = fmaxf(m, e);
  }
  for (int d = 1; d < 64; d <<= 1) m = fmaxf(m, __shfl_xor(m, d));
  // pass 2: weighted sum
  float Z = 0.f;
  float accf[8];
  for (int f = 0; f < 8; f++) accf[f] = 0.f;
  for (int p = b0 + lane; p < b1; p += 64){
    const float* ic = in + (size_t)cols[p]*Fin;
    float hc[8];
    float al = 0.f;
    for (int f = 0; f < F; f++){
      float acc = 0.f;
      for (int k = 0; k < Fin; k++) acc += ic[k]*W[k*F+f];
      hc[f] = acc;
      al += acc*as[f];
    }
    float e = al + adv; e = e >= 0.f ? e : 0.2f*e;
    float w = expf(e - m);
    Z += w;
    for (int f = 0; f < F; f++) accf[f] += w*hc[f];
  }
  if (lane == 0){
    float w = expf(es - m);
    Z += w;
    for (int f = 0; f < F; f++) accf[f] += w*hwr[f];
  }
  for (int d = 1; d < 64; d <<= 1){
    Z += __shfl_xor(Z, d);
    for (int f = 0; f < F; f++) accf[f] += __shfl_xor(accf[f], d);
  }
  if (lane < F){
    float v = accf[lane]/(Z + 1e-16f) + bias[lane];
    if (act) v = fmaxf(v, 0.f);
    hout[(size_t)row*F + lane] = v;
  }
}

// ---------------- TransformerConv row-gather + root skip -------------------
__global__ __launch_bounds__(256) void k_tc_gather(
    const int* __restrict__ rowptr, const int* __restrict__ cols,
    const float* __restrict__ tq, const float* __restrict__ tk,
    const float* __restrict__ tv, const float* __restrict__ h3,
    const float* __restrict__ Wts, const float* __restrict__ bts, float* xt){
  int row = blockIdx.x*4 + (threadIdx.x >> 6);
  int lane = threadIdx.x & 63;
  int b0 = rowptr[row], b1 = rowptr[row+1];
  const float* qr = tq + (size_t)row*5;
  float q0=qr[0], q1=qr[1], q2=qr[2], q3=qr[3], q4=qr[4];
  const float* ks = tk + (size_t)row*5;
  float es = (q0*ks[0]+q1*ks[1]+q2*ks[2]+q3*ks[3]+q4*ks[4])*0.44721360f;
  float m = es;
  for (int p = b0 + lane; p < b1; p += 64){
    const float* kr = tk + (size_t)cols[p]*5;
    float e = (q0*kr[0]+q1*kr[1]+q2*kr[2]+q3*kr[3]+q4*kr[4])*0.44721360f;
    m = fmaxf(m, e);
  }
  for (int d = 1; d < 64; d <<= 1) m = fmaxf(m, __shfl_xor(m, d));
  float Z = 0.f;
  float accf[5];
  for (int f = 0; f < 5; f++) accf[f] = 0.f;
  for (int p = b0 + lane; p < b1; p += 64){
    int c = cols[p];
    const float* kr = tk + (size_t)c*5;
    float e = (q0*kr[0]+q1*kr[1]+q2*kr[2]+q3*kr[3]+q4*kr[4])*0.44721360f;
    float w = expf(e - m);
    Z += w;
    const float* vr = tv + (size_t)c*5;
    for (int f = 0; f < 5; f++) accf[f] += w*vr[f];
  }
  if (lane == 0){
    float w = expf(es - m);
    Z += w;
    const float* vr = tv + (size_t)row*5;
    for (int f = 0; f < 5; f++) accf[f] += w*vr[f];
  }
  for (int d = 1; d < 64; d <<= 1){
    Z += __shfl_xor(Z, d);
    for (int f = 0; f < 5; f++) accf[f] += __shfl_xor(accf[f], d);
  }
  if (lane < 5){
    const float* hr = h3 + (size_t)row*5;
    float skip = bts[lane];
    for (int k2 = 0; k2 < 5; k2++) skip += hr[k2]*Wts[k2*5 + lane];
    xt[(size_t)row*5 + lane] = accf[lane]/(Z + 1e-16f) + skip;
  }
}

// ---------------- GCN row-gathers ----------------
__global__ __launch_bounds__(256) void k_gcn16(
    const int* __restrict__ rowptr, const int* __restrict__ cols,
    const float* __restrict__ P16, const float* __restrict__ d2g,
    const float* __restrict__ bg1, float* z16){
  int row = blockIdx.x*4 + (threadIdx.x >> 6);
  int lane = threadIdx.x & 63;
  int b0 = rowptr[row], b1 = rowptr[row+1];
  float dr = d2g[row];
  float acc[16];
  for (int f = 0; f < 16; f++) acc[f] = 0.f;
  for (int p = b0 + lane; p < b1; p += 64){
    int c = cols[p];
    float w = d2g[c];
    const float* pr = P16 + (size_t)c*16;
    for (int f = 0; f < 16; f++) acc[f] += w*pr[f];
  }
  if (lane == 0){
    const float* pr = P16 + (size_t)row*16;
    for (int f = 0; f < 16; f++) acc[f] += dr*pr[f];
  }
  for (int d = 1; d < 64; d <<= 1)
    for (int f = 0; f < 16; f++) acc[f] += __shfl_xor(acc[f], d);
  if (lane < 16)
    z16[(size_t)row*16 + lane] = fmaxf(dr*acc[lane] + bg1[lane], 0.f);
}
__global__ __launch_bounds__(256) void k_gcn1(
    const int* __restrict__ rowptr, const int* __restrict__ cols,
    const float* __restrict__ p1, const float* __restrict__ d2g,
    const float* __restrict__ bg2, float* u, unsigned* mku, int* crit){
  int row = blockIdx.x*4 + (threadIdx.x >> 6);
  int lane = threadIdx.x & 63;
  if (blockIdx.x == 0 && threadIdx.x == 0) crit[0] = N;
  int b0 = rowptr[row], b1 = rowptr[row+1];
  float s = 0.f;
  for (int p = b0 + lane; p < b1; p += 64) s += d2g[cols[p]]*p1[cols[p]];
  if (lane == 0) s += d2g[row]*p1[row];
  for (int d = 1; d < 64; d <<= 1) s += __shfl_xor(s, d);
  float uv = d2g[row]*s + bg2[0];
  if (lane == 0){
    u[row] = uv;
    atomicMax(mku, fkey(uv));
  }
}
__global__ void k_crit(const float* u, const unsigned* mk, int* crit, float* bonus){
  int i = blockIdx.x*TPB + threadIdx.x;
  if (i == 0){
    float um = fkeyinv(mk[0]);
    bonus[0] = ((0.8f - um) < 0.2f) ? 10.f : 0.f;
  }
  if (i >= N) return;
  if (u[i] == fkeyinv(mk[0])) atomicMin(crit, i);
}

// ---------------- dense MHA ----------------
__global__ __launch_bounds__(256) void k_mha(const float* qb, const float* kb,
                                             const float* vb, float* av){
  __shared__ float s[N];
  __shared__ float sh[4];
  __shared__ float red[4];
  int i = blockIdx.x;
  const float* qr = qb + (size_t)i*5;
  float q0=qr[0], q1=qr[1], q2=qr[2], q3=qr[3], q4=qr[4];
  float lmax = -1e30f;
  for (int j = threadIdx.x; j < N; j += TPB){
    const float* kr = kb + (size_t)j*5;
    float sc = (q0*kr[0]+q1*kr[1]+q2*kr[2]+q3*kr[3]+q4*kr[4])*0.44721360f;
    s[j] = sc;
    lmax = fmaxf(lmax, sc);
  }
  for (int off = 32; off > 0; off >>= 1) lmax = fmaxf(lmax, __shfl_down(lmax, off));
  int lane = threadIdx.x & 63, w = threadIdx.x >> 6;
  if (lane == 0) red[w] = lmax;
  __syncthreads();
  float m = fmaxf(fmaxf(red[0], red[1]), fmaxf(red[2], red[3]));
  float Zp = 0.f, a0=0.f, a1=0.f, a2=0.f, a3=0.f, a4=0.f;
  for (int j = threadIdx.x; j < N; j += TPB){
    float p = expf(s[j] - m);
    const float* vr = vb + (size_t)j*5;
    Zp += p; a0 += p*vr[0]; a1 += p*vr[1]; a2 += p*vr[2]; a3 += p*vr[3]; a4 += p*vr[4];
  }
  float Z  = block_sum(Zp, sh);
  float A0 = block_sum(a0, sh);
  float A1 = block_sum(a1, sh);
  float A2 = block_sum(a2, sh);
  float A3 = block_sum(a3, sh);
  float A4 = block_sum(a4, sh);
  if (threadIdx.x == 0){
    float inv = 1.f/Z;
    float* o = av + (size_t)i*5;
    o[0]=A0*inv; o[1]=A1*inv; o[2]=A2*inv; o[3]=A3*inv; o[4]=A4*inv;
  }
}

// ---------------- final logits + value ----------------
__global__ __launch_bounds__(256) void k_logits(const float* hm, const float* W2,
    const float* b2, const float* mask, const float* Wc, const int* crit,
    const float* bonus, float* out, float* vacc){
  __shared__ float sh[4];
  int j = blockIdx.x*TPB + threadIdx.x;
  int i = blockIdx.y;
  const float* hr = hm + (size_t)i*64;
  float acc = b2[j];
  for (int c = 0; c < 64; c++) acc += hr[c]*W2[c*N + j];
  if (i == crit[0]) acc += bonus[0];
  out[(size_t)i*N + j] = acc*mask[j];
  float s = block_sum(acc*Wc[j], sh);
  if (threadIdx.x == 0) atomicAdd(vacc, s);
}
__global__ void k_value(const float* vacc, const float* bc, float* out){
  out[(size_t)N*N] = vacc[0]/(float)N + bc[0];
}

// ---------------------------------------------------------------------------
extern "C" void kernel_launch(void* const* d_in, const int* in_sizes, int n_in,
                              void* d_out, int out_size, void* d_ws, size_t ws_size,
                              hipStream_t stream){
  const float* x    = (const float*)d_in[0];
  const int*   ei   = (const int*)d_in[1];
  const float* mask = (const float*)d_in[2];
  const float* Wg1=(const float*)d_in[3];  const float* bg1=(const float*)d_in[4];
  const float* Wg2=(const float*)d_in[5];  const float* bg2=(const float*)d_in[6];
  const float* Wa1=(const float*)d_in[7];  const float* as1=(const float*)d_in[8];
  const float* ad1=(const float*)d_in[9];  const float* ba1=(const float*)d_in[10];
  const float* Wa2=(const float*)d_in[11]; const float* as2=(const float*)d_in[12];
  const float* ad2=(const float*)d_in[13]; const float* ba2=(const float*)d_in[14];
  const float* Wq=(const float*)d_in[15];  const float* bq=(const float*)d_in[16];
  const float* Wk=(const float*)d_in[17];  const float* bk=(const float*)d_in[18];
  const float* Wv=(const float*)d_in[19];  const float* bv=(const float*)d_in[20];
  const float* Wo=(const float*)d_in[21];  const float* bo=(const float*)d_in[22];
  const float* Wtq=(const float*)d_in[23]; const float* btq=(const float*)d_in[24];
  const float* Wtk=(const float*)d_in[25]; const float* btk=(const float*)d_in[26];
  const float* Wtv=(const float*)d_in[27]; const float* btv=(const float*)d_in[28];
  const float* Wts=(const float*)d_in[29]; const float* bts=(const float*)d_in[30];
  const float* W1=(const float*)d_in[31];  const float* b1=(const float*)d_in[32];
  const float* W2=(const float*)d_in[33];  const float* b2=(const float*)d_in[34];
  const float* Wc=(const float*)d_in[35];  const float* bc=(const float*)d_in[36];
  float* out = (float*)d_out;
  float* ws  = (float*)d_ws;

  // ---- ws layout (floats) ----
  float* deg  = ws;           float* dinv = ws + 2048;
  float* d2g  = ws + 4096;    float* v1   = ws + 6144;
  float* y    = ws + 8192;    float* v2   = ws + 10240;
  float* alpha= ws + 12448;   float* beta = ws + 12576;
  float* scal = ws + 12704;                        // 16 scalar slots
  unsigned* mku = (unsigned*)(scal + 8);
  unsigned* mkv = (unsigned*)(scal + 9);
  int* crit = (int*)(scal + 10);
  int* v2i  = (int*)(scal + 11);
  float* zsm  = ws + 12720;                        // 128
  float* h2   = ws + 21040;   float* qb   = ws + 31280;
  float* kb   = ws + 41520;   float* vb   = ws + 51760;
  float* h3   = ws + 62000;   float* tqb  = ws + 72240;
  float* tkb  = ws + 82480;   float* tvb  = ws + 92720;
  float* xt   = ws + 102960;  float* p1   = ws + 113200;
  float* u    = ws + 115248;  float* hm   = ws + 117296;   // 131072

  // ---- big scratch carved from d_out[0..N*N): consumed before k_logits ----
  float* Qsl  = out;                    // NB*KL*CH = 131072
  float* hw   = out + 262144;           // 16384 (MHA attn out)
  float* h8   = out + 278528;           // 16384
  float* P16  = out + 294912;           // 32768
  float* z16  = out + 327680;           // 32768
  float* xc   = out + 360448;           // 10240
  unsigned* bar = (unsigned*)(out + 370688);  // 64
  int* rowptr = (int*)(out + 370752);   // 2049
  int* fill   = (int*)(out + 372864);   // 2048
  int* cols   = (int*)(out + 374912);   // 131072 -> ends 505984
  float* parts  = out + 507904;         // (KL+2)*NB
  float* parts2 = out + 510080;         // (KL+2)*NB
  float* npart  = out + 512256;         // 16

  // ================= setup =================
  k_init<<<8, TPB, 0, stream>>>(deg, scal, bar);
  k_deg<<<NE/TPB, TPB, 0, stream>>>(ei, deg);
  k_nodeinit<<<8, TPB, 0, stream>>>(deg, dinv, d2g, v1);
  k_rowptr<<<1, TPB, 0, stream>>>(deg, rowptr, fill);
  k_csr<<<NE/TPB, TPB, 0, stream>>>(ei, fill, cols);

  // ================= Lanczos + teig + ritz + xc (one launch) ===============
  k_lanczos<<<NB, TPB, 0, stream>>>(rowptr, cols, dinv, v1, x, Qsl, y,
                                    parts, parts2, npart, alpha, beta, zsm,
                                    v2, xc, out, scal, mkv, v2i, bar);

  const int gN5  = (N*5 + TPB-1)/TPB;
  const int gRow = N/4;

  // ================= GAT layers (fused lin+scores+gather) =================
  k_gat_fused<<<gRow, TPB, 0, stream>>>(rowptr, cols, xc, Wa1, as1, ad1, ba1, h8, 5, 8, 1);
  k_gat_fused<<<gRow, TPB, 0, stream>>>(rowptr, cols, h8, Wa2, as2, ad2, ba2, h2, 8, 5, 0);

  // ================= MultiheadAttention + TC projections =================
  k_lin3<<<gN5, TPB, 0, stream>>>(h2, Wq, bq, qb, Wk, bk, kb, Wv, bv, vb);
  k_mha<<<N, TPB, 0, stream>>>(qb, kb, vb, hw);
  k_h3tc<<<8, TPB, 0, stream>>>(hw, Wo, bo, Wtq, btq, Wtk, btk, Wtv, btv,
                                h3, tqb, tkb, tvb);

  // ================= TransformerConv (fused skip) =================
  k_tc_gather<<<gRow, TPB, 0, stream>>>(rowptr, cols, tqb, tkb, tvb, h3, Wts, bts, xt);

  // ================= GCN uncertainty net =================
  k_lin<<<(N*16 + TPB-1)/TPB, TPB, 0, stream>>>(xt, Wg1, nullptr, P16, 5, 16, 0, N*16);
  k_gcn16<<<gRow, TPB, 0, stream>>>(rowptr, cols, P16, d2g, bg1, z16);
  k_lin<<<8, TPB, 0, stream>>>(z16, Wg2, nullptr, p1, 16, 1, 0, N);
  k_gcn1<<<gRow, TPB, 0, stream>>>(rowptr, cols, p1, d2g, bg2, u, mku, crit);
  k_crit<<<8, TPB, 0, stream>>>(u, mku, crit, scal + 5);

  // ================= MLP head + logits + value =================
  k_lin<<<(N*64 + TPB-1)/TPB, TPB, 0, stream>>>(xt, W1, b1, hm, 5, 64, 1, N*64);
  k_logits<<<dim3(8, N), TPB, 0, stream>>>(hm, W2, b2, mask, Wc, crit, scal + 5, out, scal + 6);
  k_value<<<1, 1, 0, stream>>>(scal + 6, bc, out);
}